// Round 4
// baseline (357.752 us; speedup 1.0000x reference)
//
#include <hip/hip_runtime.h>
#include <math.h>

// FNO spectral block: B=4, S=16, C=64, R=128, MODES=16
// bid = n*64+c, n = b*16+s. Mode slot m = kxi*16+ky, kx_eff = kxi<16 ? kxi : 96+kxi.
// K1: MFMA DFT + compacted residual (no scatter). K3: inverse + residual gather.

#define TWO_PI_OVER_128 0.04908738521234052f
#define RCAP 1280

typedef __attribute__((ext_vector_type(8))) short bf16x8;
typedef __attribute__((ext_vector_type(4))) float f32x4;
union FragU { uint4 u; bf16x8 s; };

__device__ __forceinline__ unsigned pk(float a, float b) {
  unsigned ua = __float_as_uint(a), ub = __float_as_uint(b);
  ua = (ua + 0x7FFFu + ((ua >> 16) & 1u)) >> 16;
  ub = (ub + 0x7FFFu + ((ub >> 16) & 1u)) >> 16;
  return ua | (ub << 16);
}
__device__ __forceinline__ float2 upk(unsigned v) {
  return make_float2(__uint_as_float(v << 16), __uint_as_float(v & 0xFFFF0000u));
}
__device__ __forceinline__ unsigned bf1(float a) {
  unsigned ua = __float_as_uint(a);
  return (ua + 0x7FFFu + ((ua >> 16) & 1u)) >> 16;
}

// ---------------- Scan: scomb[p]=(s<<12)|rank, plist[s][r]=p, cntg[s] ---------
__global__ __launch_bounds__(1024) void kscan(const int* __restrict__ lu,
                                              int* __restrict__ scomb,
                                              int* __restrict__ plist,
                                              int* __restrict__ cntg) {
  __shared__ unsigned short cnt[16][64];
  const int tid = threadIdx.x;
  const int s = tid >> 6, seg = tid & 63;
  const int base = seg * 256;
  int c = 0;
  for (int i = 0; i < 256; ++i) c += (lu[base + i] == s) ? 1 : 0;
  cnt[s][seg] = (unsigned short)c;
  __syncthreads();
  int r = 0;
  for (int j = 0; j < seg; ++j) r += cnt[s][j];
  for (int i = 0; i < 256; ++i) {
    const int p = base + i;
    if (lu[p] == s) {
      scomb[p] = (s << 12) | r;
      if (r < RCAP) plist[s * RCAP + r] = p;
      ++r;
    }
  }
  if (seg == 63) cntg[s] = (r < RCAP) ? r : RCAP;
}

// ---------------- Twiddle tables: Et[32 w][128 y], Gt[64 jr][128 x] (bf16) -----
__global__ __launch_bounds__(256) void ktab(unsigned* __restrict__ Etu,
                                            unsigned* __restrict__ Gtu) {
  const int tid = threadIdx.x;
  for (int i = 0; i < 8; ++i) {
    int t = i * 256 + tid;
    int w = t >> 6, y0 = (t & 63) * 2;
    float v[2];
#pragma unroll
    for (int q = 0; q < 2; ++q) {
      int y = y0 + q;
      if (w < 16) v[q] = cosf((float)((w * y) & 127) * TWO_PI_OVER_128);
      else        v[q] = -sinf((float)(((w - 16) * y) & 127) * TWO_PI_OVER_128);
    }
    Etu[t] = bf1(v[0]) | (bf1(v[1]) << 16);
  }
  for (int i = 0; i < 16; ++i) {
    int t = i * 256 + tid;
    int jr = t >> 6, x0 = (t & 63) * 2;
    int j = (jr & 31);
    int kx = (j < 16) ? j : 96 + j;
    float v[2];
#pragma unroll
    for (int q = 0; q < 2; ++q) {
      int x = x0 + q;
      float a = (float)((kx * x) & 127) * TWO_PI_OVER_128;
      v[q] = (jr < 32) ? cosf(a) : sinf(a);
    }
    Gtu[t] = bf1(v[0]) | (bf1(v[1]) << 16);
  }
}

// ---------------- Weights transpose: w[c][o][kx][ky] -> Wt[m][o][c], wsc folded ---
__global__ __launch_bounds__(256) void ktw(const float* __restrict__ w1r,
                                           const float* __restrict__ w1i,
                                           const float* __restrict__ w2r,
                                           const float* __restrict__ w2i,
                                           unsigned* __restrict__ Wt) {
  __shared__ unsigned tile[64 * 65];
  const int o = blockIdx.x & 63, wsel = blockIdx.x >> 6;
  const float* Wr = wsel ? w2r : w1r;
  const float* Wi = wsel ? w2i : w1i;
  const int tid = threadIdx.x;
  for (int mc = 0; mc < 4; ++mc) {
    if (mc) __syncthreads();
    for (int i = 0; i < 16; ++i) {
      int idx = i * 256 + tid;
      int c = idx >> 6, ml = idx & 63;
      int mh = mc * 64 + ml;
      float wsc = ((mh & 15) ? 2.f : 1.f) / 16384.f;
      size_t off = (size_t)(c * 64 + o) * 256 + mh;
      tile[c * 65 + ml] = pk(Wr[off] * wsc, Wi[off] * wsc);
    }
    __syncthreads();
    for (int i = 0; i < 16; ++i) {
      int idx = i * 256 + tid;
      int ml = idx >> 6, c = idx & 63;
      Wt[(size_t)(wsel * 256 + mc * 64 + ml) * 4096 + o * 64 + c] = tile[c * 65 + ml];
    }
  }
}

// ---------------- Stage 1: rfft2 via MFMA + compacted residual ----------------
__global__ __launch_bounds__(256) void k1_fwd(const float* __restrict__ ref,
                                              const unsigned* __restrict__ Etu,
                                              const unsigned* __restrict__ Gtu,
                                              const int* __restrict__ cntg,
                                              const int* __restrict__ plist,
                                              unsigned short* __restrict__ Rcomp,
                                              unsigned* __restrict__ Xf) {
  __shared__ unsigned short imgL[128 * 128];  // bf16, XOR-swizzled; tail reused as Xout
  __shared__ unsigned short A1t[32 * 128];    // A1^T [w][x] bf16, swizzled
  unsigned* Xout = (unsigned*)imgL;           // alias (imgL dead after step 1)
  const int bid = blockIdx.x;
  const int n = bid >> 6, c = bid & 63;
  const int b = n >> 4, s = n & 15;
  const int tid = threadIdx.x;
  const int l = tid & 63, w = tid >> 6;

  // Preload E fragments (B-operand) — all waves
  FragU Ef[2][4];
#pragma unroll
  for (int nt = 0; nt < 2; ++nt)
#pragma unroll
    for (int ks = 0; ks < 4; ++ks)
      Ef[nt][ks].u = *(const uint4*)&Etu[(nt * 16 + (l & 15)) * 64 + ks * 16 + (l >> 4) * 4];
  // Preload G fragments (A-operand) — waves 0,1 only
  FragU Gf[2][4];
  if (w < 2) {
#pragma unroll
    for (int mtl = 0; mtl < 2; ++mtl)
#pragma unroll
      for (int ks = 0; ks < 4; ++ks)
        Gf[mtl][ks].u = *(const uint4*)&Gtu[((w + 2 * mtl) * 16 + (l & 15)) * 64 + ks * 16 + (l >> 4) * 4];
  }

  // Stage image -> LDS bf16 (swizzled), lean loop
  const float* imf = ref + (size_t)bid * 16384;
  const float4* im4 = (const float4*)imf;
  for (int i = 0; i < 16; ++i) {
    const int e4 = i * 256 + tid;
    float4 v = im4[e4];
    const int p = e4 * 4;
    const int x = p >> 7, y0 = p & 127;
    const int chunk = (y0 >> 3) ^ (x & 15);
    uint2 pkd = make_uint2(pk(v.x, v.y), pk(v.z, v.w));
    *(uint2*)&imgL[x * 128 + chunk * 8 + (y0 & 7)] = pkd;
  }
  // Compacted residual: gather matching pixels (L1/L2-hot) -> Rcomp[b][c][s][r]
  {
    const int ns = cntg[s];
    unsigned short* rc = Rcomp + ((size_t)(b * 64 + c) * 16 + s) * RCAP;
    for (int r = tid; r < ns; r += 256) {
      const int p = plist[s * RCAP + r];
      rc[r] = (unsigned short)bf1(imf[p]);
    }
  }
  __syncthreads();

  // Step 1: A1 = img(128x128) * E(128x32); wave w -> M-tiles {2w, 2w+1}
  f32x4 acc1[2][2] = {};
#pragma unroll
  for (int mtl = 0; mtl < 2; ++mtl) {
    const int mt = w * 2 + mtl;
    const int x = mt * 16 + (l & 15);
#pragma unroll
    for (int ks = 0; ks < 4; ++ks) {
      const int chunk = (ks * 4 + (l >> 4)) ^ (x & 15);
      FragU a;
      a.u = *(const uint4*)&imgL[x * 128 + chunk * 8];
#pragma unroll
      for (int nt = 0; nt < 2; ++nt)
        acc1[mtl][nt] = __builtin_amdgcn_mfma_f32_16x16x32_bf16(a.s, Ef[nt][ks].s, acc1[mtl][nt], 0, 0, 0);
    }
  }
#pragma unroll
  for (int mtl = 0; mtl < 2; ++mtl) {
    const int x0 = (w * 2 + mtl) * 16 + (l >> 4) * 4;
#pragma unroll
    for (int nt = 0; nt < 2; ++nt) {
      const int wp = nt * 16 + (l & 15);
      const int chunk = (x0 >> 3) ^ (wp & 15);
      uint2 w2 = make_uint2(pk(acc1[mtl][nt][0], acc1[mtl][nt][1]),
                            pk(acc1[mtl][nt][2], acc1[mtl][nt][3]));
      *(uint2*)&A1t[wp * 128 + chunk * 8 + (x0 & 7)] = w2;
    }
  }
  __syncthreads();

  // Step 2: P = G(64x128) * A1(128x32); waves 0,1: M-tiles {w, w+2}
  if (w < 2) {
    f32x4 acc2[2][2] = {};
#pragma unroll
    for (int mtl = 0; mtl < 2; ++mtl)
#pragma unroll
      for (int ks = 0; ks < 4; ++ks) {
#pragma unroll
        for (int nt = 0; nt < 2; ++nt) {
          const int wp = nt * 16 + (l & 15);
          const int chunk = (ks * 4 + (l >> 4)) ^ (wp & 15);
          FragU bfr;
          bfr.u = *(const uint4*)&A1t[wp * 128 + chunk * 8];
          acc2[mtl][nt] = __builtin_amdgcn_mfma_f32_16x16x32_bf16(Gf[mtl][ks].s, bfr.s, acc2[mtl][nt], 0, 0, 0);
        }
      }
#pragma unroll
    for (int r = 0; r < 4; ++r) {
      const int j = w * 16 + (l >> 4) * 4 + r;   // kxi 0..31
      const int ky = l & 15;
      const float re = acc2[0][0][r] + acc2[1][1][r];
      const float im = acc2[0][1][r] - acc2[1][0][r];
      Xout[j * 16 + ky] = pk(re, im);
    }
  }
  __syncthreads();
  ((uint2*)(Xf + (size_t)bid * 512))[tid] = ((uint2*)Xout)[tid];
}

// ---------------- Transpose Xf[bid][m] -> Xf2[m][bid] -------------------------
__global__ __launch_bounds__(256) void kt(const unsigned* __restrict__ Xf,
                                          unsigned* __restrict__ Xf2) {
  __shared__ unsigned tile[64 * 65];
  const int bm = blockIdx.x & 7, bn = blockIdx.x >> 3;
  const int tid = threadIdx.x;
  for (int i = 0; i < 16; ++i) {
    int idx = i * 256 + tid;
    int r = idx >> 6, cc = idx & 63;
    tile[r * 65 + cc] = Xf[(size_t)(bn * 64 + r) * 512 + bm * 64 + cc];
  }
  __syncthreads();
  for (int i = 0; i < 16; ++i) {
    int idx = i * 256 + tid;
    int r = idx >> 6, cc = idx & 63;
    Xf2[(size_t)(bm * 64 + r) * 4096 + bn * 64 + cc] = tile[cc * 65 + r];
  }
}

// ---------------- Stage 2: per-mode complex channel mix ------------------------
__global__ __launch_bounds__(256) void k2_mix(const unsigned* __restrict__ Xf2,
                                              const unsigned* __restrict__ Wt,
                                              unsigned* __restrict__ Yf) {
  __shared__ float2 Xs[64 * 65];
  __shared__ float2 Ws[64 * 65];
  const int m = blockIdx.x;
  const int tid = threadIdx.x;
  for (int i = 0; i < 16; ++i) {
    int e = i * 256 + tid;
    Xs[(e >> 6) * 65 + (e & 63)] = upk(Xf2[(size_t)m * 4096 + e]);
    Ws[(e >> 6) * 65 + (e & 63)] = upk(Wt[(size_t)m * 4096 + e]);
  }
  __syncthreads();
  const int g = tid >> 4, t = tid & 15;
  float accr[4][4] = {}, acci[4][4] = {};
  for (int cc = 0; cc < 64; ++cc) {
    float2 xv[4], wv[4];
#pragma unroll
    for (int k = 0; k < 4; ++k) xv[k] = Xs[(g + 16 * k) * 65 + cc];
#pragma unroll
    for (int j = 0; j < 4; ++j) wv[j] = Ws[(t + 16 * j) * 65 + cc];
#pragma unroll
    for (int k = 0; k < 4; ++k)
#pragma unroll
      for (int j = 0; j < 4; ++j) {
        accr[k][j] += xv[k].x * wv[j].x - xv[k].y * wv[j].y;
        acci[k][j] += xv[k].x * wv[j].y + xv[k].y * wv[j].x;
      }
  }
  __syncthreads();
  unsigned* Os = (unsigned*)Xs;
#pragma unroll
  for (int k = 0; k < 4; ++k)
#pragma unroll
    for (int j = 0; j < 4; ++j) {
      int bo = k * 64 + t + 16 * j;
      Os[bo * 17 + g] = pk(accr[k][j], acci[k][j]);
    }
  __syncthreads();
  for (int i = 0; i < 16; ++i) {
    int e = i * 256 + tid;
    int bo = e >> 4, ss = e & 15;
    Yf[(size_t)bo * 8192 + m * 16 + ss] = Os[bo * 17 + ss];
  }
}

// ---------------- Stage 3: partial irfft2 + residual + store --------------------
__global__ __launch_bounds__(512) void k3_inv(const unsigned* __restrict__ Yf,
                                              const int* __restrict__ scomb,
                                              const unsigned short* __restrict__ Rcomp,
                                              float* __restrict__ out) {
  __shared__ float2 Ys[16 * 512];   // [s][m ^ s]
  __shared__ float tbuf[16 * 138];
  __shared__ float2 tab[128];
  const int bo = blockIdx.x >> 1, half = blockIdx.x & 1;
  const int tid = threadIdx.x;
  if (tid < 128) {
    float sv, cv;
    sincosf((float)tid * TWO_PI_OVER_128, &sv, &cv);
    tab[tid] = make_float2(cv, sv);
  }
  for (int i = 0; i < 16; ++i) {
    int e = i * 512 + tid;
    int ss = e & 15, mm = e >> 4;
    Ys[ss * 512 + (mm ^ ss)] = upk(Yf[(size_t)bo * 8192 + e]);
  }
  __syncthreads();
  const int ky = tid & 15, xl = (tid >> 4) & 3, sg = tid >> 6;
  const int ss0 = sg, ss1 = sg + 8;
  float* outb = out + (size_t)bo * 16384;
  const unsigned short* rcb = Rcomp + (size_t)bo * 16 * RCAP;

  for (int xb = half * 16; xb < half * 16 + 16; ++xb) {
    {
      const int x = xb * 4 + xl;
      const float2 stp = tab[x];
      float c0 = 1.f, s0 = 0.f;
      float tre0 = 0.f, tim0 = 0.f, tre1 = 0.f, tim1 = 0.f;
#pragma unroll
      for (int kxi = 0; kxi < 32; ++kxi) {
        if (kxi == 16) {
          float2 st = tab[(112 * x) & 127];
          c0 = st.x; s0 = st.y;
        }
        const int mb = kxi * 16 + ky;
        const float2 Y0 = Ys[ss0 * 512 + (mb ^ ss0)];
        const float2 Y1 = Ys[ss1 * 512 + (mb ^ ss1)];
        tre0 = fmaf(Y0.x, c0, fmaf(-Y0.y, s0, tre0));
        tim0 = fmaf(Y0.x, s0, fmaf(Y0.y, c0, tim0));
        tre1 = fmaf(Y1.x, c0, fmaf(-Y1.y, s0, tre1));
        tim1 = fmaf(Y1.x, s0, fmaf(Y1.y, c0, tim1));
        float nc = c0 * stp.x - s0 * stp.y, ns = s0 * stp.x + c0 * stp.y;
        c0 = nc; s0 = ns;
      }
      tbuf[ss0 * 138 + xl * 34 + ky * 2] = tre0;
      tbuf[ss0 * 138 + xl * 34 + ky * 2 + 1] = tim0;
      tbuf[ss1 * 138 + xl * 34 + ky * 2] = tre1;
      tbuf[ss1 * 138 + xl * 34 + ky * 2 + 1] = tim1;
    }
    __syncthreads();
    {
      const int xl2 = tid >> 7, y = tid & 127;
      const int p = (xb * 4 + xl2) * 128 + y;
      const int sc = scomb[p];
      const int ssel = sc >> 12;
      const float rres = __uint_as_float((unsigned)rcb[ssel * RCAP + (sc & 4095)] << 16);
      const float* tb = tbuf + ssel * 138 + xl2 * 34;
      const float2 stpy = tab[y];
      float acc = 0.f, c0 = 1.f, s0 = 0.f;
#pragma unroll
      for (int k2 = 0; k2 < 16; ++k2) {
        const float tre = tb[k2 * 2], tim = tb[k2 * 2 + 1];
        acc = fmaf(tre, c0, fmaf(-tim, s0, acc));
        float nc = c0 * stpy.x - s0 * stpy.y, ns = s0 * stpy.x + c0 * stpy.y;
        c0 = nc; s0 = ns;
      }
      outb[p] = rres + acc;
    }
    __syncthreads();
  }
}

extern "C" void kernel_launch(void* const* d_in, const int* in_sizes, int n_in,
                              void* d_out, int out_size, void* d_ws, size_t ws_size,
                              hipStream_t stream) {
  const float* ref = (const float*)d_in[0];
  const int* lu = (const int*)d_in[2];
  const float* w1r = (const float*)d_in[3];
  const float* w1i = (const float*)d_in[4];
  const float* w2r = (const float*)d_in[5];
  const float* w2i = (const float*)d_in[6];
  float* out = (float*)d_out;

  unsigned* Xf  = (unsigned*)d_ws;            // [4096][512]; reused as Yf after kt
  unsigned* Xf2 = Xf  + (size_t)4096 * 512;   // [512][4096]
  unsigned* Wt  = Xf2 + (size_t)4096 * 512;   // [512][64][64]
  unsigned* Etu = Wt  + (size_t)4096 * 512;   // 2048
  unsigned* Gtu = Etu + 2048;                 // 4096
  int* cntg     = (int*)(Gtu + 4096);         // 16
  int* plist    = cntg + 16;                  // 16*RCAP
  int* scomb    = plist + 16 * RCAP;          // 16384
  unsigned short* Rcomp = (unsigned short*)(scomb + 16384);  // 256*16*RCAP bf16
  unsigned* Yf  = Xf;                          // alias (Xf dead after kt)

  ktab<<<1, 256, 0, stream>>>(Etu, Gtu);
  kscan<<<1, 1024, 0, stream>>>(lu, scomb, plist, cntg);
  ktw<<<128, 256, 0, stream>>>(w1r, w1i, w2r, w2i, Wt);
  k1_fwd<<<4096, 256, 0, stream>>>(ref, Etu, Gtu, cntg, plist, Rcomp, Xf);
  kt<<<512, 256, 0, stream>>>(Xf, Xf2);
  k2_mix<<<512, 256, 0, stream>>>(Xf2, Wt, Yf);
  k3_inv<<<512, 512, 0, stream>>>(Yf, scomb, Rcomp, out);
}

// Round 5
// 205.519 us; speedup vs baseline: 1.7407x; 1.7407x over previous
//
#include <hip/hip_runtime.h>
#include <math.h>

// FNO spectral block: B=4, S=16, C=64, R=128, MODES=16
// bid = n*64+c, n = b*16+s. Mode slot m = kxi*16+ky, kx_eff = kxi<16 ? kxi : 96+kxi.
// K1: MFMA DFT + compacted residual (no scatter). K3: inverse + residual gather.

#define TWO_PI_OVER_128 0.04908738521234052f
#define RCAP 1280

typedef __attribute__((ext_vector_type(8))) short bf16x8;
typedef __attribute__((ext_vector_type(4))) float f32x4;
union FragU { uint4 u; bf16x8 s; };

__device__ __forceinline__ unsigned pk(float a, float b) {
  unsigned ua = __float_as_uint(a), ub = __float_as_uint(b);
  ua = (ua + 0x7FFFu + ((ua >> 16) & 1u)) >> 16;
  ub = (ub + 0x7FFFu + ((ub >> 16) & 1u)) >> 16;
  return ua | (ub << 16);
}
__device__ __forceinline__ float2 upk(unsigned v) {
  return make_float2(__uint_as_float(v << 16), __uint_as_float(v & 0xFFFF0000u));
}
__device__ __forceinline__ unsigned bf1(float a) {
  unsigned ua = __float_as_uint(a);
  return (ua + 0x7FFFu + ((ua >> 16) & 1u)) >> 16;
}

// ---------------- Scan (parallel): one block per s ----------------------------
// scomb[p]=(s<<12)|rank, plist[s][r]=p, cntg[s]=count
__global__ __launch_bounds__(1024) void kscan(const int* __restrict__ lu,
                                              int* __restrict__ scomb,
                                              int* __restrict__ plist,
                                              int* __restrict__ cntg) {
  __shared__ int wsum[16];
  const int s = blockIdx.x;
  const int tid = threadIdx.x;
  const int lane = tid & 63, wid = tid >> 6;
  // 16 contiguous pixels per thread via 4x int4
  const int4* lu4 = (const int4*)lu + tid * 4;
  unsigned match = 0;
#pragma unroll
  for (int q = 0; q < 4; ++q) {
    int4 v = lu4[q];
    match |= (v.x == s ? 1u : 0u) << (4 * q);
    match |= (v.y == s ? 1u : 0u) << (4 * q + 1);
    match |= (v.z == s ? 1u : 0u) << (4 * q + 2);
    match |= (v.w == s ? 1u : 0u) << (4 * q + 3);
  }
  const int cnt = __popc(match);
  int pre = cnt;
#pragma unroll
  for (int d = 1; d < 64; d <<= 1) {
    int t = __shfl_up(pre, d, 64);
    if (lane >= d) pre += t;
  }
  if (lane == 63) wsum[wid] = pre;
  __syncthreads();
  int woff = 0;
  for (int j = 0; j < wid; ++j) woff += wsum[j];
  int r = woff + pre - cnt;             // exclusive prefix = rank of first match
  const int base = tid * 16;
#pragma unroll
  for (int i = 0; i < 16; ++i) {
    if ((match >> i) & 1u) {
      const int p = base + i;
      scomb[p] = (s << 12) | r;
      if (r < RCAP) plist[s * RCAP + r] = p;
      ++r;
    }
  }
  if (tid == 1023) {
    const int tot = woff + pre;
    cntg[s] = (tot < RCAP) ? tot : RCAP;
  }
}

// ---------------- Twiddle tables: Et[32 w][128 y], Gt[64 jr][128 x] (bf16) -----
__global__ __launch_bounds__(256) void ktab(unsigned* __restrict__ Etu,
                                            unsigned* __restrict__ Gtu) {
  const int tid = threadIdx.x;
  for (int i = 0; i < 8; ++i) {
    int t = i * 256 + tid;
    int w = t >> 6, y0 = (t & 63) * 2;
    float v[2];
#pragma unroll
    for (int q = 0; q < 2; ++q) {
      int y = y0 + q;
      if (w < 16) v[q] = cosf((float)((w * y) & 127) * TWO_PI_OVER_128);
      else        v[q] = -sinf((float)(((w - 16) * y) & 127) * TWO_PI_OVER_128);
    }
    Etu[t] = bf1(v[0]) | (bf1(v[1]) << 16);
  }
  for (int i = 0; i < 16; ++i) {
    int t = i * 256 + tid;
    int jr = t >> 6, x0 = (t & 63) * 2;
    int j = (jr & 31);
    int kx = (j < 16) ? j : 96 + j;
    float v[2];
#pragma unroll
    for (int q = 0; q < 2; ++q) {
      int x = x0 + q;
      float a = (float)((kx * x) & 127) * TWO_PI_OVER_128;
      v[q] = (jr < 32) ? cosf(a) : sinf(a);
    }
    Gtu[t] = bf1(v[0]) | (bf1(v[1]) << 16);
  }
}

// ---------------- Weights transpose: w[c][o][kx][ky] -> Wt[m][o][c], wsc folded ---
__global__ __launch_bounds__(256) void ktw(const float* __restrict__ w1r,
                                           const float* __restrict__ w1i,
                                           const float* __restrict__ w2r,
                                           const float* __restrict__ w2i,
                                           unsigned* __restrict__ Wt) {
  __shared__ unsigned tile[64 * 65];
  const int o = blockIdx.x & 63, wsel = blockIdx.x >> 6;
  const float* Wr = wsel ? w2r : w1r;
  const float* Wi = wsel ? w2i : w1i;
  const int tid = threadIdx.x;
  for (int mc = 0; mc < 4; ++mc) {
    if (mc) __syncthreads();
    for (int i = 0; i < 16; ++i) {
      int idx = i * 256 + tid;
      int c = idx >> 6, ml = idx & 63;
      int mh = mc * 64 + ml;
      float wsc = ((mh & 15) ? 2.f : 1.f) / 16384.f;
      size_t off = (size_t)(c * 64 + o) * 256 + mh;
      tile[c * 65 + ml] = pk(Wr[off] * wsc, Wi[off] * wsc);
    }
    __syncthreads();
    for (int i = 0; i < 16; ++i) {
      int idx = i * 256 + tid;
      int ml = idx >> 6, c = idx & 63;
      Wt[(size_t)(wsel * 256 + mc * 64 + ml) * 4096 + o * 64 + c] = tile[c * 65 + ml];
    }
  }
}

// ---------------- Stage 1: rfft2 via MFMA + compacted residual ----------------
__global__ __launch_bounds__(256) void k1_fwd(const float* __restrict__ ref,
                                              const unsigned* __restrict__ Etu,
                                              const unsigned* __restrict__ Gtu,
                                              const int* __restrict__ cntg,
                                              const int* __restrict__ plist,
                                              unsigned short* __restrict__ Rcomp,
                                              unsigned* __restrict__ Xf) {
  __shared__ unsigned short imgL[128 * 128];  // bf16, XOR-swizzled; reused as Xout
  __shared__ unsigned short A1t[32 * 128];    // A1^T [w][x] bf16, swizzled
  unsigned* Xout = (unsigned*)imgL;           // alias (imgL dead after step 1)
  const int bid = blockIdx.x;
  const int n = bid >> 6, c = bid & 63;
  const int b = n >> 4, s = n & 15;
  const int tid = threadIdx.x;
  const int l = tid & 63, w = tid >> 6;

  // Preload E fragments (B-operand) — all waves
  FragU Ef[2][4];
#pragma unroll
  for (int nt = 0; nt < 2; ++nt)
#pragma unroll
    for (int ks = 0; ks < 4; ++ks)
      Ef[nt][ks].u = *(const uint4*)&Etu[(nt * 16 + (l & 15)) * 64 + ks * 16 + (l >> 4) * 4];
  // Preload G fragments (A-operand) — waves 0,1 only
  FragU Gf[2][4];
  if (w < 2) {
#pragma unroll
    for (int mtl = 0; mtl < 2; ++mtl)
#pragma unroll
      for (int ks = 0; ks < 4; ++ks)
        Gf[mtl][ks].u = *(const uint4*)&Gtu[((w + 2 * mtl) * 16 + (l & 15)) * 64 + ks * 16 + (l >> 4) * 4];
  }

  // Stage image -> LDS bf16 (swizzled), lean loop
  const float* imf = ref + (size_t)bid * 16384;
  const float4* im4 = (const float4*)imf;
  for (int i = 0; i < 16; ++i) {
    const int e4 = i * 256 + tid;
    float4 v = im4[e4];
    const int p = e4 * 4;
    const int x = p >> 7, y0 = p & 127;
    const int chunk = (y0 >> 3) ^ (x & 15);
    uint2 pkd = make_uint2(pk(v.x, v.y), pk(v.z, v.w));
    *(uint2*)&imgL[x * 128 + chunk * 8 + (y0 & 7)] = pkd;
  }
  // Compacted residual: gather matching pixels (L1/L2-hot) -> Rcomp[b][c][s][r]
  {
    const int ns = cntg[s];
    unsigned short* rc = Rcomp + ((size_t)(b * 64 + c) * 16 + s) * RCAP;
    for (int r = tid; r < ns; r += 256) {
      const int p = plist[s * RCAP + r];
      rc[r] = (unsigned short)bf1(imf[p]);
    }
  }
  __syncthreads();

  // Step 1: A1 = img(128x128) * E(128x32); wave w -> M-tiles {2w, 2w+1}
  f32x4 acc1[2][2] = {};
#pragma unroll
  for (int mtl = 0; mtl < 2; ++mtl) {
    const int mt = w * 2 + mtl;
    const int x = mt * 16 + (l & 15);
#pragma unroll
    for (int ks = 0; ks < 4; ++ks) {
      const int chunk = (ks * 4 + (l >> 4)) ^ (x & 15);
      FragU a;
      a.u = *(const uint4*)&imgL[x * 128 + chunk * 8];
#pragma unroll
      for (int nt = 0; nt < 2; ++nt)
        acc1[mtl][nt] = __builtin_amdgcn_mfma_f32_16x16x32_bf16(a.s, Ef[nt][ks].s, acc1[mtl][nt], 0, 0, 0);
    }
  }
#pragma unroll
  for (int mtl = 0; mtl < 2; ++mtl) {
    const int x0 = (w * 2 + mtl) * 16 + (l >> 4) * 4;
#pragma unroll
    for (int nt = 0; nt < 2; ++nt) {
      const int wp = nt * 16 + (l & 15);
      const int chunk = (x0 >> 3) ^ (wp & 15);
      uint2 w2 = make_uint2(pk(acc1[mtl][nt][0], acc1[mtl][nt][1]),
                            pk(acc1[mtl][nt][2], acc1[mtl][nt][3]));
      *(uint2*)&A1t[wp * 128 + chunk * 8 + (x0 & 7)] = w2;
    }
  }
  __syncthreads();

  // Step 2: P = G(64x128) * A1(128x32); waves 0,1: M-tiles {w, w+2}
  if (w < 2) {
    f32x4 acc2[2][2] = {};
#pragma unroll
    for (int mtl = 0; mtl < 2; ++mtl)
#pragma unroll
      for (int ks = 0; ks < 4; ++ks) {
#pragma unroll
        for (int nt = 0; nt < 2; ++nt) {
          const int wp = nt * 16 + (l & 15);
          const int chunk = (ks * 4 + (l >> 4)) ^ (wp & 15);
          FragU bfr;
          bfr.u = *(const uint4*)&A1t[wp * 128 + chunk * 8];
          acc2[mtl][nt] = __builtin_amdgcn_mfma_f32_16x16x32_bf16(Gf[mtl][ks].s, bfr.s, acc2[mtl][nt], 0, 0, 0);
        }
      }
#pragma unroll
    for (int r = 0; r < 4; ++r) {
      const int j = w * 16 + (l >> 4) * 4 + r;   // kxi 0..31
      const int ky = l & 15;
      const float re = acc2[0][0][r] + acc2[1][1][r];
      const float im = acc2[0][1][r] - acc2[1][0][r];
      Xout[j * 16 + ky] = pk(re, im);
    }
  }
  __syncthreads();
  ((uint2*)(Xf + (size_t)bid * 512))[tid] = ((uint2*)Xout)[tid];
}

// ---------------- Transpose Xf[bid][m] -> Xf2[m][bid] -------------------------
__global__ __launch_bounds__(256) void kt(const unsigned* __restrict__ Xf,
                                          unsigned* __restrict__ Xf2) {
  __shared__ unsigned tile[64 * 65];
  const int bm = blockIdx.x & 7, bn = blockIdx.x >> 3;
  const int tid = threadIdx.x;
  for (int i = 0; i < 16; ++i) {
    int idx = i * 256 + tid;
    int r = idx >> 6, cc = idx & 63;
    tile[r * 65 + cc] = Xf[(size_t)(bn * 64 + r) * 512 + bm * 64 + cc];
  }
  __syncthreads();
  for (int i = 0; i < 16; ++i) {
    int idx = i * 256 + tid;
    int r = idx >> 6, cc = idx & 63;
    Xf2[(size_t)(bm * 64 + r) * 4096 + bn * 64 + cc] = tile[cc * 65 + r];
  }
}

// ---------------- Stage 2: per-mode complex channel mix ------------------------
__global__ __launch_bounds__(256) void k2_mix(const unsigned* __restrict__ Xf2,
                                              const unsigned* __restrict__ Wt,
                                              unsigned* __restrict__ Yf) {
  __shared__ float2 Xs[64 * 65];
  __shared__ float2 Ws[64 * 65];
  const int m = blockIdx.x;
  const int tid = threadIdx.x;
  for (int i = 0; i < 16; ++i) {
    int e = i * 256 + tid;
    Xs[(e >> 6) * 65 + (e & 63)] = upk(Xf2[(size_t)m * 4096 + e]);
    Ws[(e >> 6) * 65 + (e & 63)] = upk(Wt[(size_t)m * 4096 + e]);
  }
  __syncthreads();
  const int g = tid >> 4, t = tid & 15;
  float accr[4][4] = {}, acci[4][4] = {};
  for (int cc = 0; cc < 64; ++cc) {
    float2 xv[4], wv[4];
#pragma unroll
    for (int k = 0; k < 4; ++k) xv[k] = Xs[(g + 16 * k) * 65 + cc];
#pragma unroll
    for (int j = 0; j < 4; ++j) wv[j] = Ws[(t + 16 * j) * 65 + cc];
#pragma unroll
    for (int k = 0; k < 4; ++k)
#pragma unroll
      for (int j = 0; j < 4; ++j) {
        accr[k][j] += xv[k].x * wv[j].x - xv[k].y * wv[j].y;
        acci[k][j] += xv[k].x * wv[j].y + xv[k].y * wv[j].x;
      }
  }
  __syncthreads();
  unsigned* Os = (unsigned*)Xs;
#pragma unroll
  for (int k = 0; k < 4; ++k)
#pragma unroll
    for (int j = 0; j < 4; ++j) {
      int bo = k * 64 + t + 16 * j;
      Os[bo * 17 + g] = pk(accr[k][j], acci[k][j]);
    }
  __syncthreads();
  for (int i = 0; i < 16; ++i) {
    int e = i * 256 + tid;
    int bo = e >> 4, ss = e & 15;
    Yf[(size_t)bo * 8192 + m * 16 + ss] = Os[bo * 17 + ss];
  }
}

// ---------------- Stage 3: partial irfft2 + residual + store --------------------
__global__ __launch_bounds__(512) void k3_inv(const unsigned* __restrict__ Yf,
                                              const int* __restrict__ scomb,
                                              const unsigned short* __restrict__ Rcomp,
                                              float* __restrict__ out) {
  __shared__ float2 Ys[16 * 512];   // [s][m ^ s]
  __shared__ float tbuf[16 * 138];
  __shared__ float2 tab[128];
  const int bo = blockIdx.x >> 1, half = blockIdx.x & 1;
  const int tid = threadIdx.x;
  if (tid < 128) {
    float sv, cv;
    sincosf((float)tid * TWO_PI_OVER_128, &sv, &cv);
    tab[tid] = make_float2(cv, sv);
  }
  for (int i = 0; i < 16; ++i) {
    int e = i * 512 + tid;
    int ss = e & 15, mm = e >> 4;
    Ys[ss * 512 + (mm ^ ss)] = upk(Yf[(size_t)bo * 8192 + e]);
  }
  __syncthreads();
  const int ky = tid & 15, xl = (tid >> 4) & 3, sg = tid >> 6;
  const int ss0 = sg, ss1 = sg + 8;
  float* outb = out + (size_t)bo * 16384;
  const unsigned short* rcb = Rcomp + (size_t)bo * 16 * RCAP;

  for (int xb = half * 16; xb < half * 16 + 16; ++xb) {
    {
      const int x = xb * 4 + xl;
      const float2 stp = tab[x];
      float c0 = 1.f, s0 = 0.f;
      float tre0 = 0.f, tim0 = 0.f, tre1 = 0.f, tim1 = 0.f;
#pragma unroll
      for (int kxi = 0; kxi < 32; ++kxi) {
        if (kxi == 16) {
          float2 st = tab[(112 * x) & 127];
          c0 = st.x; s0 = st.y;
        }
        const int mb = kxi * 16 + ky;
        const float2 Y0 = Ys[ss0 * 512 + (mb ^ ss0)];
        const float2 Y1 = Ys[ss1 * 512 + (mb ^ ss1)];
        tre0 = fmaf(Y0.x, c0, fmaf(-Y0.y, s0, tre0));
        tim0 = fmaf(Y0.x, s0, fmaf(Y0.y, c0, tim0));
        tre1 = fmaf(Y1.x, c0, fmaf(-Y1.y, s0, tre1));
        tim1 = fmaf(Y1.x, s0, fmaf(Y1.y, c0, tim1));
        float nc = c0 * stp.x - s0 * stp.y, ns = s0 * stp.x + c0 * stp.y;
        c0 = nc; s0 = ns;
      }
      tbuf[ss0 * 138 + xl * 34 + ky * 2] = tre0;
      tbuf[ss0 * 138 + xl * 34 + ky * 2 + 1] = tim0;
      tbuf[ss1 * 138 + xl * 34 + ky * 2] = tre1;
      tbuf[ss1 * 138 + xl * 34 + ky * 2 + 1] = tim1;
    }
    __syncthreads();
    {
      const int xl2 = tid >> 7, y = tid & 127;
      const int p = (xb * 4 + xl2) * 128 + y;
      const int sc = scomb[p];
      const int ssel = sc >> 12;
      const float rres = __uint_as_float((unsigned)rcb[ssel * RCAP + (sc & 4095)] << 16);
      const float* tb = tbuf + ssel * 138 + xl2 * 34;
      const float2 stpy = tab[y];
      float acc = 0.f, c0 = 1.f, s0 = 0.f;
#pragma unroll
      for (int k2 = 0; k2 < 16; ++k2) {
        const float tre = tb[k2 * 2], tim = tb[k2 * 2 + 1];
        acc = fmaf(tre, c0, fmaf(-tim, s0, acc));
        float nc = c0 * stpy.x - s0 * stpy.y, ns = s0 * stpy.x + c0 * stpy.y;
        c0 = nc; s0 = ns;
      }
      outb[p] = rres + acc;
    }
    __syncthreads();
  }
}

extern "C" void kernel_launch(void* const* d_in, const int* in_sizes, int n_in,
                              void* d_out, int out_size, void* d_ws, size_t ws_size,
                              hipStream_t stream) {
  const float* ref = (const float*)d_in[0];
  const int* lu = (const int*)d_in[2];
  const float* w1r = (const float*)d_in[3];
  const float* w1i = (const float*)d_in[4];
  const float* w2r = (const float*)d_in[5];
  const float* w2i = (const float*)d_in[6];
  float* out = (float*)d_out;

  unsigned* Xf  = (unsigned*)d_ws;            // [4096][512]; reused as Yf after kt
  unsigned* Xf2 = Xf  + (size_t)4096 * 512;   // [512][4096]
  unsigned* Wt  = Xf2 + (size_t)4096 * 512;   // [512][64][64]
  unsigned* Etu = Wt  + (size_t)4096 * 512;   // 2048
  unsigned* Gtu = Etu + 2048;                 // 4096
  int* cntg     = (int*)(Gtu + 4096);         // 16
  int* plist    = cntg + 16;                  // 16*RCAP
  int* scomb    = plist + 16 * RCAP;          // 16384
  unsigned short* Rcomp = (unsigned short*)(scomb + 16384);  // 256*16*RCAP bf16
  unsigned* Yf  = Xf;                          // alias (Xf dead after kt)

  kscan<<<16, 1024, 0, stream>>>(lu, scomb, plist, cntg);
  ktab<<<1, 256, 0, stream>>>(Etu, Gtu);
  ktw<<<128, 256, 0, stream>>>(w1r, w1i, w2r, w2i, Wt);
  k1_fwd<<<4096, 256, 0, stream>>>(ref, Etu, Gtu, cntg, plist, Rcomp, Xf);
  kt<<<512, 256, 0, stream>>>(Xf, Xf2);
  k2_mix<<<512, 256, 0, stream>>>(Xf2, Wt, Yf);
  k3_inv<<<512, 512, 0, stream>>>(Yf, scomb, Rcomp, out);
}

// Round 6
// 203.843 us; speedup vs baseline: 1.7550x; 1.0082x over previous
//
#include <hip/hip_runtime.h>
#include <math.h>

// FNO spectral block: B=4, S=16, C=64, R=128, MODES=16
// bid = n*64+c, n = b*16+s. Mode slot m = kxi*16+ky, kx_eff = kxi<16 ? kxi : 96+kxi.
// K1: MFMA rfft2 (x-split, 24KB LDS) + compacted residual from LDS.
// K3: MFMA inverse-x (G2 x Y) + per-pixel ky-inverse + residual gather.

#define TWO_PI_OVER_128 0.04908738521234052f
#define RCAP 1280

typedef __attribute__((ext_vector_type(8))) short bf16x8;
typedef __attribute__((ext_vector_type(4))) float f32x4;
union FragU { uint4 u; bf16x8 s; };

__device__ __forceinline__ unsigned pk(float a, float b) {
  unsigned ua = __float_as_uint(a), ub = __float_as_uint(b);
  ua = (ua + 0x7FFFu + ((ua >> 16) & 1u)) >> 16;
  ub = (ub + 0x7FFFu + ((ub >> 16) & 1u)) >> 16;
  return ua | (ub << 16);
}
__device__ __forceinline__ float2 upk(unsigned v) {
  return make_float2(__uint_as_float(v << 16), __uint_as_float(v & 0xFFFF0000u));
}
__device__ __forceinline__ unsigned bf1(float a) {
  unsigned ua = __float_as_uint(a);
  return (ua + 0x7FFFu + ((ua >> 16) & 1u)) >> 16;
}

// ---------------- Scan (parallel): one block per s ----------------------------
// scomb[p]=(s<<12)|rank, plist[s][r]=p, cntg[s]=count, cnthg[s]=count with p<8192
__global__ __launch_bounds__(1024) void kscan(const int* __restrict__ lu,
                                              int* __restrict__ scomb,
                                              int* __restrict__ plist,
                                              int* __restrict__ cntg,
                                              int* __restrict__ cnthg) {
  __shared__ int wsum[16];
  const int s = blockIdx.x;
  const int tid = threadIdx.x;
  const int lane = tid & 63, wid = tid >> 6;
  const int4* lu4 = (const int4*)lu + tid * 4;
  unsigned match = 0;
#pragma unroll
  for (int q = 0; q < 4; ++q) {
    int4 v = lu4[q];
    match |= (v.x == s ? 1u : 0u) << (4 * q);
    match |= (v.y == s ? 1u : 0u) << (4 * q + 1);
    match |= (v.z == s ? 1u : 0u) << (4 * q + 2);
    match |= (v.w == s ? 1u : 0u) << (4 * q + 3);
  }
  const int cnt = __popc(match);
  int pre = cnt;
#pragma unroll
  for (int d = 1; d < 64; d <<= 1) {
    int t = __shfl_up(pre, d, 64);
    if (lane >= d) pre += t;
  }
  if (lane == 63) wsum[wid] = pre;
  __syncthreads();
  int woff = 0;
  for (int j = 0; j < wid; ++j) woff += wsum[j];
  int r = woff + pre - cnt;             // exclusive prefix
  if (tid == 512) cnthg[s] = r;         // matches among pixels < 8192
  const int base = tid * 16;
#pragma unroll
  for (int i = 0; i < 16; ++i) {
    if ((match >> i) & 1u) {
      const int p = base + i;
      scomb[p] = (s << 12) | r;
      if (r < RCAP) plist[s * RCAP + r] = p;
      ++r;
    }
  }
  if (tid == 1023) {
    const int tot = woff + pre;
    cntg[s] = (tot < RCAP) ? tot : RCAP;
  }
}

// ---------------- Twiddle tables ----------------------------------------------
// Et[32 w][128 y]: w<16 cos(w y th); w>=16 -sin((w-16) y th)      (k1 y-pass B)
// Gt[64 jr][128 x]: jr<32 cos(kx(j) x th); jr>=32 sin              (k1 x-pass A)
// G2t[128 x][64 k]: k<32 cos(kx(k) x th); k>=32 sin(kx(k-32) x th) (k3 A-operand)
__global__ __launch_bounds__(256) void ktab(unsigned* __restrict__ Etu,
                                            unsigned* __restrict__ Gtu,
                                            unsigned* __restrict__ G2tu) {
  const int tid = threadIdx.x;
  for (int i = 0; i < 8; ++i) {
    int t = i * 256 + tid;
    int w = t >> 6, y0 = (t & 63) * 2;
    float v[2];
#pragma unroll
    for (int q = 0; q < 2; ++q) {
      int y = y0 + q;
      if (w < 16) v[q] = cosf((float)((w * y) & 127) * TWO_PI_OVER_128);
      else        v[q] = -sinf((float)(((w - 16) * y) & 127) * TWO_PI_OVER_128);
    }
    Etu[t] = bf1(v[0]) | (bf1(v[1]) << 16);
  }
  for (int i = 0; i < 16; ++i) {
    int t = i * 256 + tid;
    int jr = t >> 6, x0 = (t & 63) * 2;
    int j = (jr & 31);
    int kx = (j < 16) ? j : 96 + j;
    float v[2];
#pragma unroll
    for (int q = 0; q < 2; ++q) {
      int x = x0 + q;
      float a = (float)((kx * x) & 127) * TWO_PI_OVER_128;
      v[q] = (jr < 32) ? cosf(a) : sinf(a);
    }
    Gtu[t] = bf1(v[0]) | (bf1(v[1]) << 16);
  }
  for (int i = 0; i < 16; ++i) {
    int t = i * 256 + tid;                // u32 idx = x*32 + k2
    int x = t >> 5, k2 = t & 31;
    float v[2];
#pragma unroll
    for (int q = 0; q < 2; ++q) {
      int k = k2 * 2 + q;
      int kxi = k & 31;
      int kxe = (kxi < 16) ? kxi : 96 + kxi;
      float a = (float)((kxe * x) & 127) * TWO_PI_OVER_128;
      v[q] = (k < 32) ? cosf(a) : sinf(a);
    }
    G2tu[t] = bf1(v[0]) | (bf1(v[1]) << 16);
  }
}

// ---------------- Weights transpose: w[c][o][kx][ky] -> Wt[m][o][c], wsc folded ---
__global__ __launch_bounds__(256) void ktw(const float* __restrict__ w1r,
                                           const float* __restrict__ w1i,
                                           const float* __restrict__ w2r,
                                           const float* __restrict__ w2i,
                                           unsigned* __restrict__ Wt) {
  __shared__ unsigned tile[64 * 65];
  const int o = blockIdx.x & 63, wsel = blockIdx.x >> 6;
  const float* Wr = wsel ? w2r : w1r;
  const float* Wi = wsel ? w2i : w1i;
  const int tid = threadIdx.x;
  for (int mc = 0; mc < 4; ++mc) {
    if (mc) __syncthreads();
    for (int i = 0; i < 16; ++i) {
      int idx = i * 256 + tid;
      int c = idx >> 6, ml = idx & 63;
      int mh = mc * 64 + ml;
      float wsc = ((mh & 15) ? 2.f : 1.f) / 16384.f;
      size_t off = (size_t)(c * 64 + o) * 256 + mh;
      tile[c * 65 + ml] = pk(Wr[off] * wsc, Wi[off] * wsc);
    }
    __syncthreads();
    for (int i = 0; i < 16; ++i) {
      int idx = i * 256 + tid;
      int ml = idx >> 6, c = idx & 63;
      Wt[(size_t)(wsel * 256 + mc * 64 + ml) * 4096 + o * 64 + c] = tile[c * 65 + ml];
    }
  }
}

// ---------------- Stage 1: rfft2 via MFMA (x-split) + residual from LDS -------
__global__ __launch_bounds__(256, 6) void k1_fwd(const float* __restrict__ ref,
                                                 const unsigned* __restrict__ Etu,
                                                 const unsigned* __restrict__ Gtu,
                                                 const int* __restrict__ cntg,
                                                 const int* __restrict__ cnthg,
                                                 const int* __restrict__ plist,
                                                 unsigned short* __restrict__ Rcomp,
                                                 unsigned* __restrict__ Xf) {
  __shared__ unsigned short imgL[64 * 128];   // bf16 half-image, XOR-swizzled
  __shared__ unsigned short A1t[32 * 128];    // A1^T [w'][x] bf16, swizzled
  unsigned* Xout = (unsigned*)imgL;           // alias (imgL dead after last mfma)
  const int bid = blockIdx.x;
  const int n = bid >> 6, c = bid & 63;
  const int b = n >> 4, s = n & 15;
  const int tid = threadIdx.x;
  const int l = tid & 63, w = tid >> 6;

  // Preload E fragments (B-operand) — all waves
  FragU Ef[2][4];
#pragma unroll
  for (int nt = 0; nt < 2; ++nt)
#pragma unroll
    for (int ks = 0; ks < 4; ++ks)
      Ef[nt][ks].u = *(const uint4*)&Etu[(nt * 16 + (l & 15)) * 64 + ks * 16 + (l >> 4) * 4];
  // Preload G fragments (A-operand) — waves 0,1 only
  FragU Gf[2][4];
  if (w < 2) {
#pragma unroll
    for (int mtl = 0; mtl < 2; ++mtl)
#pragma unroll
      for (int ks = 0; ks < 4; ++ks)
        Gf[mtl][ks].u = *(const uint4*)&Gtu[((w + 2 * mtl) * 16 + (l & 15)) * 64 + ks * 16 + (l >> 4) * 4];
  }

  const float* imf = ref + (size_t)bid * 16384;
  const int ns = cntg[s], nh = cnthg[s];
  unsigned short* rc = Rcomp + ((size_t)(b * 64 + c) * 16 + s) * RCAP;
  const int* pl = plist + s * RCAP;

  for (int half = 0; half < 2; ++half) {
    if (half) __syncthreads();                 // imgL readers of half 0 done
    const float4* im4 = (const float4*)(imf + half * 8192);
    for (int i = 0; i < 8; ++i) {
      const int e4 = i * 256 + tid;
      float4 v = im4[e4];
      const int pl2 = e4 * 4;
      const int xl = pl2 >> 7, y0 = pl2 & 127;
      const int chunk = (y0 >> 3) ^ (xl & 15);
      *(uint2*)&imgL[xl * 128 + chunk * 8 + (y0 & 7)] =
          make_uint2(pk(v.x, v.y), pk(v.z, v.w));
    }
    __syncthreads();
    // y-pass MFMA: wave w -> M-tile (half*4 + w)
    f32x4 acc1[2] = {};
    const int xl = w * 16 + (l & 15);
#pragma unroll
    for (int ks = 0; ks < 4; ++ks) {
      const int chunk = (ks * 4 + (l >> 4)) ^ (xl & 15);
      FragU a;
      a.u = *(const uint4*)&imgL[xl * 128 + chunk * 8];
#pragma unroll
      for (int nt = 0; nt < 2; ++nt)
        acc1[nt] = __builtin_amdgcn_mfma_f32_16x16x32_bf16(a.s, Ef[nt][ks].s, acc1[nt], 0, 0, 0);
    }
    {
      const int x0 = (half * 4 + w) * 16 + (l >> 4) * 4;
#pragma unroll
      for (int nt = 0; nt < 2; ++nt) {
        const int wp = nt * 16 + (l & 15);
        const int chunk = (x0 >> 3) ^ (wp & 15);
        *(uint2*)&A1t[wp * 128 + chunk * 8 + (x0 & 7)] =
            make_uint2(pk(acc1[nt][0], acc1[nt][1]), pk(acc1[nt][2], acc1[nt][3]));
      }
    }
    // residual gather for this half straight from LDS (bf16 already)
    {
      const int rlo = half ? nh : 0, rhi = half ? ns : nh;
      for (int r = rlo + tid; r < rhi; r += 256) {
        const int p = pl[r];
        const int gxl = (p >> 7) - half * 64, y = p & 127;
        rc[r] = imgL[gxl * 128 + (((y >> 3) ^ (gxl & 15))) * 8 + (y & 7)];
      }
    }
  }
  __syncthreads();

  // x-pass MFMA: P = G(64x128) * A1(128x32); waves 0,1: M-tiles {w, w+2}
  if (w < 2) {
    f32x4 acc2[2][2] = {};
#pragma unroll
    for (int mtl = 0; mtl < 2; ++mtl)
#pragma unroll
      for (int ks = 0; ks < 4; ++ks) {
#pragma unroll
        for (int nt = 0; nt < 2; ++nt) {
          const int wp = nt * 16 + (l & 15);
          const int chunk = (ks * 4 + (l >> 4)) ^ (wp & 15);
          FragU bfr;
          bfr.u = *(const uint4*)&A1t[wp * 128 + chunk * 8];
          acc2[mtl][nt] = __builtin_amdgcn_mfma_f32_16x16x32_bf16(Gf[mtl][ks].s, bfr.s, acc2[mtl][nt], 0, 0, 0);
        }
      }
#pragma unroll
    for (int r = 0; r < 4; ++r) {
      const int j = w * 16 + (l >> 4) * 4 + r;   // kxi 0..31
      const int ky = l & 15;
      const float re = acc2[0][0][r] + acc2[1][1][r];
      const float im = acc2[0][1][r] - acc2[1][0][r];
      Xout[j * 16 + ky] = pk(re, im);
    }
  }
  __syncthreads();
  ((uint2*)(Xf + (size_t)bid * 512))[tid] = ((uint2*)Xout)[tid];
}

// ---------------- Transpose Xf[bid][m] -> Xf2[m][bid] -------------------------
__global__ __launch_bounds__(256) void kt(const unsigned* __restrict__ Xf,
                                          unsigned* __restrict__ Xf2) {
  __shared__ unsigned tile[64 * 65];
  const int bm = blockIdx.x & 7, bn = blockIdx.x >> 3;
  const int tid = threadIdx.x;
  for (int i = 0; i < 16; ++i) {
    int idx = i * 256 + tid;
    int r = idx >> 6, cc = idx & 63;
    tile[r * 65 + cc] = Xf[(size_t)(bn * 64 + r) * 512 + bm * 64 + cc];
  }
  __syncthreads();
  for (int i = 0; i < 16; ++i) {
    int idx = i * 256 + tid;
    int r = idx >> 6, cc = idx & 63;
    Xf2[(size_t)(bm * 64 + r) * 4096 + bn * 64 + cc] = tile[cc * 65 + r];
  }
}

// ---------------- Stage 2: per-mode complex channel mix ------------------------
__global__ __launch_bounds__(256) void k2_mix(const unsigned* __restrict__ Xf2,
                                              const unsigned* __restrict__ Wt,
                                              unsigned* __restrict__ Yf) {
  __shared__ float2 Xs[64 * 65];
  __shared__ float2 Ws[64 * 65];
  const int m = blockIdx.x;
  const int tid = threadIdx.x;
  for (int i = 0; i < 16; ++i) {
    int e = i * 256 + tid;
    Xs[(e >> 6) * 65 + (e & 63)] = upk(Xf2[(size_t)m * 4096 + e]);
    Ws[(e >> 6) * 65 + (e & 63)] = upk(Wt[(size_t)m * 4096 + e]);
  }
  __syncthreads();
  const int g = tid >> 4, t = tid & 15;
  float accr[4][4] = {}, acci[4][4] = {};
  for (int cc = 0; cc < 64; ++cc) {
    float2 xv[4], wv[4];
#pragma unroll
    for (int k = 0; k < 4; ++k) xv[k] = Xs[(g + 16 * k) * 65 + cc];
#pragma unroll
    for (int j = 0; j < 4; ++j) wv[j] = Ws[(t + 16 * j) * 65 + cc];
#pragma unroll
    for (int k = 0; k < 4; ++k)
#pragma unroll
      for (int j = 0; j < 4; ++j) {
        accr[k][j] += xv[k].x * wv[j].x - xv[k].y * wv[j].y;
        acci[k][j] += xv[k].x * wv[j].y + xv[k].y * wv[j].x;
      }
  }
  __syncthreads();
  unsigned* Os = (unsigned*)Xs;
#pragma unroll
  for (int k = 0; k < 4; ++k)
#pragma unroll
    for (int j = 0; j < 4; ++j) {
      int bo = k * 64 + t + 16 * j;
      Os[bo * 17 + g] = pk(accr[k][j], acci[k][j]);
    }
  __syncthreads();
  for (int i = 0; i < 16; ++i) {
    int e = i * 256 + tid;
    int bo = e >> 4, ss = e & 15;
    Yf[(size_t)bo * 8192 + m * 16 + ss] = Os[bo * 17 + ss];
  }
}

// ---------------- Stage 3: MFMA inverse-x + per-pixel inverse-y + residual ----
__global__ __launch_bounds__(1024, 4) void k3_inv(const unsigned* __restrict__ Yf,
                                                  const unsigned* __restrict__ G2tu,
                                                  const int* __restrict__ scomb,
                                                  const unsigned short* __restrict__ Rcomp,
                                                  float* __restrict__ out) {
  __shared__ __align__(16) unsigned short Ypb[16 * 32 * 40]; // [s][col][kxi], pad-40
  __shared__ __align__(16) unsigned short tbuf[16 * 546];    // [s][16x][2ky+c], u32-stride 273
  __shared__ float2 tab[128];
  const int bo = blockIdx.x >> 1, half = blockIdx.x & 1;
  const int tid = threadIdx.x;
  const int l = tid & 63, w = tid >> 6;    // w = wave id = s for phase A
  if (tid < 128) {
    float sv, cv;
    sincosf((float)tid * TWO_PI_OVER_128, &sv, &cv);
    tab[tid] = make_float2(cv, sv);
  }
  // Build Ypb from Yf[bo]: cols 0-15 = Yr[ky], 16-31 = Yi[ky]; rows = kxi
  {
    const unsigned* src = Yf + (size_t)bo * 8192;
    for (int i = 0; i < 8; ++i) {
      int e = i * 1024 + tid;               // = m*16 + s
      unsigned v = src[e];
      int ss = e & 15, m = e >> 4, kxi = m >> 4, ky = m & 15;
      unsigned short* yb = Ypb + ss * 1280;
      yb[ky * 40 + kxi] = (unsigned short)(v & 0xFFFFu);
      yb[(16 + ky) * 40 + kxi] = (unsigned short)(v >> 16);
    }
  }
  __syncthreads();
  float* outb = out + (size_t)bo * 16384;
  const unsigned short* rcb = Rcomp + (size_t)bo * 16 * RCAP;
  unsigned* tb32 = (unsigned*)tbuf;

  for (int ch = 0; ch < 4; ++ch) {
    const int xb = half * 64 + ch * 16;
    // phase A: wave w computes t[s=w][16 x][16 ky] via 4 MFMAs
    {
      const int xg = xb + (l & 15);
      FragU Ac, As, B0, B1;
      Ac.u = *(const uint4*)&G2tu[xg * 32 + (l >> 4) * 4];
      As.u = *(const uint4*)&G2tu[xg * 32 + 16 + (l >> 4) * 4];
      const unsigned short* yb = Ypb + w * 1280;
      B0.u = *(const uint4*)&yb[(l & 15) * 40 + (l >> 4) * 8];
      B1.u = *(const uint4*)&yb[(16 + (l & 15)) * 40 + (l >> 4) * 8];
      f32x4 z = {};
      f32x4 d1  = __builtin_amdgcn_mfma_f32_16x16x32_bf16(Ac.s, B0.s, z, 0, 0, 0); // Σc·Yr
      f32x4 d1b = __builtin_amdgcn_mfma_f32_16x16x32_bf16(Ac.s, B1.s, z, 0, 0, 0); // Σc·Yi
      f32x4 d2  = __builtin_amdgcn_mfma_f32_16x16x32_bf16(As.s, B0.s, z, 0, 0, 0); // Σs·Yr
      f32x4 d2b = __builtin_amdgcn_mfma_f32_16x16x32_bf16(As.s, B1.s, z, 0, 0, 0); // Σs·Yi
      const int ky = l & 15;
#pragma unroll
      for (int r = 0; r < 4; ++r) {
        const int xloc = (l >> 4) * 4 + r;
        tb32[w * 273 + xloc * 17 + ky] = pk(d1[r] - d2b[r], d1b[r] + d2[r]);
      }
    }
    __syncthreads();
    // phase B: 16 x-rows × 128 y; wave w owns x-row w; 2 px/thread
    {
      const int xg = xb + w;
      const int pbase = xg * 128 + l * 2;
      const int2 sc2 = *(const int2*)&scomb[pbase];
      float o2[2];
#pragma unroll
      for (int q = 0; q < 2; ++q) {
        const int y = l * 2 + q;
        const int sc = q ? sc2.y : sc2.x;
        const int ssel = sc >> 12;
        const float rres = __uint_as_float((unsigned)rcb[ssel * RCAP + (sc & 4095)] << 16);
        const unsigned* tb = tb32 + ssel * 273 + w * 17;
        const float2 stpy = tab[y];
        float acc = 0.f, c0 = 1.f, s0 = 0.f;
#pragma unroll
        for (int k2 = 0; k2 < 16; ++k2) {
          const float2 tt = upk(tb[k2]);
          acc = fmaf(tt.x, c0, fmaf(-tt.y, s0, acc));
          float nc = c0 * stpy.x - s0 * stpy.y, ns = s0 * stpy.x + c0 * stpy.y;
          c0 = nc; s0 = ns;
        }
        o2[q] = rres + acc;
      }
      *(float2*)&outb[pbase] = make_float2(o2[0], o2[1]);
    }
    __syncthreads();
  }
}

extern "C" void kernel_launch(void* const* d_in, const int* in_sizes, int n_in,
                              void* d_out, int out_size, void* d_ws, size_t ws_size,
                              hipStream_t stream) {
  const float* ref = (const float*)d_in[0];
  const int* lu = (const int*)d_in[2];
  const float* w1r = (const float*)d_in[3];
  const float* w1i = (const float*)d_in[4];
  const float* w2r = (const float*)d_in[5];
  const float* w2i = (const float*)d_in[6];
  float* out = (float*)d_out;

  unsigned* Xf  = (unsigned*)d_ws;            // [4096][512]; reused as Yf after kt
  unsigned* Xf2 = Xf  + (size_t)4096 * 512;   // [512][4096]
  unsigned* Wt  = Xf2 + (size_t)4096 * 512;   // [512][64][64]
  unsigned* Etu = Wt  + (size_t)4096 * 512;   // 2048
  unsigned* Gtu = Etu + 2048;                 // 4096
  unsigned* G2tu = Gtu + 4096;                // 4096
  int* cntg     = (int*)(G2tu + 4096);        // 16
  int* cnthg    = cntg + 16;                  // 16
  int* plist    = cnthg + 16;                 // 16*RCAP
  int* scomb    = plist + 16 * RCAP;          // 16384
  unsigned short* Rcomp = (unsigned short*)(scomb + 16384);  // 256*16*RCAP bf16
  unsigned* Yf  = Xf;                          // alias (Xf dead after kt)

  kscan<<<16, 1024, 0, stream>>>(lu, scomb, plist, cntg, cnthg);
  ktab<<<1, 256, 0, stream>>>(Etu, Gtu, G2tu);
  ktw<<<128, 256, 0, stream>>>(w1r, w1i, w2r, w2i, Wt);
  k1_fwd<<<4096, 256, 0, stream>>>(ref, Etu, Gtu, cntg, cnthg, plist, Rcomp, Xf);
  kt<<<512, 256, 0, stream>>>(Xf, Xf2);
  k2_mix<<<512, 256, 0, stream>>>(Xf2, Wt, Yf);
  k3_inv<<<512, 1024, 0, stream>>>(Yf, G2tu, scomb, Rcomp, out);
}

// Round 7
// 129.266 us; speedup vs baseline: 2.7676x; 1.5769x over previous
//
#include <hip/hip_runtime.h>
#include <math.h>

// FNO spectral block: B=4, S=16, C=64, R=128, MODES=16
// bid = n*64+c, n = b*16+s. Mode slot m = kxi*16+ky, kx_eff = kxi<16 ? kxi : 96+kxi.
// K1: MFMA rfft2, 2 images/block, all-wave x-pass. K3: MFMA inverse-x + VALU inverse-y.

#define TWO_PI_OVER_128 0.04908738521234052f
#define RCAP 1280

typedef __attribute__((ext_vector_type(8))) short bf16x8;
typedef __attribute__((ext_vector_type(4))) float f32x4;
union FragU { uint4 u; bf16x8 s; };

__device__ __forceinline__ unsigned pk(float a, float b) {
  unsigned ua = __float_as_uint(a), ub = __float_as_uint(b);
  ua = (ua + 0x7FFFu + ((ua >> 16) & 1u)) >> 16;
  ub = (ub + 0x7FFFu + ((ub >> 16) & 1u)) >> 16;
  return ua | (ub << 16);
}
__device__ __forceinline__ float2 upk(unsigned v) {
  return make_float2(__uint_as_float(v << 16), __uint_as_float(v & 0xFFFF0000u));
}
__device__ __forceinline__ unsigned bf1(float a) {
  unsigned ua = __float_as_uint(a);
  return (ua + 0x7FFFu + ((ua >> 16) & 1u)) >> 16;
}

// ---------------- Fused prep: kscan (b<16) | ktab (b==16) | ktw (b>=17) --------
__global__ __launch_bounds__(1024) void kprep(const int* __restrict__ lu,
                                              int* __restrict__ scomb,
                                              int* __restrict__ plist,
                                              int* __restrict__ cntg,
                                              int* __restrict__ cnthg,
                                              unsigned* __restrict__ Etu,
                                              unsigned* __restrict__ Gtu,
                                              unsigned* __restrict__ G2tu,
                                              const float* __restrict__ w1r,
                                              const float* __restrict__ w1i,
                                              const float* __restrict__ w2r,
                                              const float* __restrict__ w2i,
                                              unsigned* __restrict__ Wt) {
  __shared__ int wsum[16];
  __shared__ unsigned tile[64 * 65];
  const int blk = blockIdx.x;
  const int tid = threadIdx.x;
  if (blk < 16) {
    // ---- scan: one block per s ----
    const int s = blk;
    const int lane = tid & 63, wid = tid >> 6;
    const int4* lu4 = (const int4*)lu + tid * 4;
    unsigned match = 0;
#pragma unroll
    for (int q = 0; q < 4; ++q) {
      int4 v = lu4[q];
      match |= (v.x == s ? 1u : 0u) << (4 * q);
      match |= (v.y == s ? 1u : 0u) << (4 * q + 1);
      match |= (v.z == s ? 1u : 0u) << (4 * q + 2);
      match |= (v.w == s ? 1u : 0u) << (4 * q + 3);
    }
    const int cnt = __popc(match);
    int pre = cnt;
#pragma unroll
    for (int d = 1; d < 64; d <<= 1) {
      int t = __shfl_up(pre, d, 64);
      if (lane >= d) pre += t;
    }
    if (lane == 63) wsum[wid] = pre;
    __syncthreads();
    int woff = 0;
    for (int j = 0; j < wid; ++j) woff += wsum[j];
    int r = woff + pre - cnt;
    if (tid == 512) cnthg[s] = r;
    const int base = tid * 16;
#pragma unroll
    for (int i = 0; i < 16; ++i) {
      if ((match >> i) & 1u) {
        const int p = base + i;
        scomb[p] = (s << 12) | r;
        if (r < RCAP) plist[s * RCAP + r] = p;
        ++r;
      }
    }
    if (tid == 1023) {
      const int tot = woff + pre;
      cntg[s] = (tot < RCAP) ? tot : RCAP;
    }
  } else if (blk == 16) {
    // ---- twiddle tables ----
    for (int i = 0; i < 2; ++i) {
      int t = i * 1024 + tid;
      int w = t >> 6, y0 = (t & 63) * 2;
      float v[2];
#pragma unroll
      for (int q = 0; q < 2; ++q) {
        int y = y0 + q;
        if (w < 16) v[q] = cosf((float)((w * y) & 127) * TWO_PI_OVER_128);
        else        v[q] = -sinf((float)(((w - 16) * y) & 127) * TWO_PI_OVER_128);
      }
      Etu[t] = bf1(v[0]) | (bf1(v[1]) << 16);
    }
    for (int i = 0; i < 4; ++i) {
      int t = i * 1024 + tid;
      int jr = t >> 6, x0 = (t & 63) * 2;
      int j = (jr & 31);
      int kx = (j < 16) ? j : 96 + j;
      float v[2];
#pragma unroll
      for (int q = 0; q < 2; ++q) {
        int x = x0 + q;
        float a = (float)((kx * x) & 127) * TWO_PI_OVER_128;
        v[q] = (jr < 32) ? cosf(a) : sinf(a);
      }
      Gtu[t] = bf1(v[0]) | (bf1(v[1]) << 16);
    }
    for (int i = 0; i < 4; ++i) {
      int t = i * 1024 + tid;               // u32 idx = x*32 + k2
      int x = t >> 5, k2 = t & 31;
      float v[2];
#pragma unroll
      for (int q = 0; q < 2; ++q) {
        int k = k2 * 2 + q;
        int kxi = k & 31;
        int kxe = (kxi < 16) ? kxi : 96 + kxi;
        float a = (float)((kxe * x) & 127) * TWO_PI_OVER_128;
        v[q] = (k < 32) ? cosf(a) : sinf(a);
      }
      G2tu[t] = bf1(v[0]) | (bf1(v[1]) << 16);
    }
  } else {
    // ---- weights transpose: old block (blk-17) in [0,128) ----
    const int ob = blk - 17;
    const int o = ob & 63, wsel = ob >> 6;
    const float* Wr = wsel ? w2r : w1r;
    const float* Wi = wsel ? w2i : w1i;
    for (int mc = 0; mc < 4; ++mc) {
      if (mc) __syncthreads();
      for (int i = 0; i < 4; ++i) {
        int idx = i * 1024 + tid;
        int c = idx >> 6, ml = idx & 63;
        int mh = mc * 64 + ml;
        float wsc = ((mh & 15) ? 2.f : 1.f) / 16384.f;
        size_t off = (size_t)(c * 64 + o) * 256 + mh;
        tile[c * 65 + ml] = pk(Wr[off] * wsc, Wi[off] * wsc);
      }
      __syncthreads();
      for (int i = 0; i < 4; ++i) {
        int idx = i * 1024 + tid;
        int ml = idx >> 6, c = idx & 63;
        Wt[(size_t)(wsel * 256 + mc * 64 + ml) * 4096 + o * 64 + c] = tile[c * 65 + ml];
      }
    }
  }
}

// ---------------- Stage 1: rfft2 via MFMA, 2 images/block ----------------------
__global__ __launch_bounds__(256, 4) void k1_fwd(const float* __restrict__ ref,
                                                 const unsigned* __restrict__ Etu,
                                                 const unsigned* __restrict__ Gtu,
                                                 const int* __restrict__ cntg,
                                                 const int* __restrict__ cnthg,
                                                 const int* __restrict__ plist,
                                                 unsigned short* __restrict__ Rcomp,
                                                 unsigned* __restrict__ Xf) {
  __shared__ unsigned short imgL[64 * 128];     // 16 KB staging (one half-image)
  __shared__ unsigned short A1t[2][32 * 128];   // per-image A1^T, 8 KB each
  unsigned* Xout = (unsigned*)imgL;             // alias; imgL dead before x-pass writes
  const int bid2 = blockIdx.x;                  // 0..2047
  const int n = bid2 >> 5, cp = bid2 & 31;
  const int c0 = cp * 2;
  const int b = n >> 4, s = n & 15;
  const int tid = threadIdx.x;
  const int l = tid & 63, w = tid >> 6;

  // Preload E fragments (B-operand) — live across both images
  FragU Ef[2][4];
#pragma unroll
  for (int nt = 0; nt < 2; ++nt)
#pragma unroll
    for (int ks = 0; ks < 4; ++ks)
      Ef[nt][ks].u = *(const uint4*)&Etu[(nt * 16 + (l & 15)) * 64 + ks * 16 + (l >> 4) * 4];

  const int ns = cntg[s], nh = cnthg[s];
  const int* pl = plist + s * RCAP;

  for (int img = 0; img < 2; ++img) {
    const int c = c0 + img;
    const float* imf = ref + (size_t)((n << 6) + c) * 16384;
    unsigned short* rc = Rcomp + ((size_t)((b << 6) + c) * 16 + s) * RCAP;
    for (int half = 0; half < 2; ++half) {
      if (img | half) __syncthreads();          // imgL free for re-stage
      const float4* im4 = (const float4*)(imf + half * 8192);
      for (int i = 0; i < 8; ++i) {
        const int e4 = i * 256 + tid;
        float4 v = im4[e4];
        const int pl2 = e4 * 4;
        const int xl = pl2 >> 7, y0 = pl2 & 127;
        const int chunk = (y0 >> 3) ^ (xl & 15);
        *(uint2*)&imgL[xl * 128 + chunk * 8 + (y0 & 7)] =
            make_uint2(pk(v.x, v.y), pk(v.z, v.w));
      }
      __syncthreads();
      // y-pass MFMA: wave w -> M-tile (half*4 + w)
      f32x4 acc1[2] = {};
      const int xl = w * 16 + (l & 15);
#pragma unroll
      for (int ks = 0; ks < 4; ++ks) {
        const int chunk = (ks * 4 + (l >> 4)) ^ (xl & 15);
        FragU a;
        a.u = *(const uint4*)&imgL[xl * 128 + chunk * 8];
#pragma unroll
        for (int nt = 0; nt < 2; ++nt)
          acc1[nt] = __builtin_amdgcn_mfma_f32_16x16x32_bf16(a.s, Ef[nt][ks].s, acc1[nt], 0, 0, 0);
      }
      {
        const int x0 = (half * 4 + w) * 16 + (l >> 4) * 4;
#pragma unroll
        for (int nt = 0; nt < 2; ++nt) {
          const int wp = nt * 16 + (l & 15);
          const int chunk = (x0 >> 3) ^ (wp & 15);
          *(uint2*)&A1t[img][wp * 128 + chunk * 8 + (x0 & 7)] =
              make_uint2(pk(acc1[nt][0], acc1[nt][1]), pk(acc1[nt][2], acc1[nt][3]));
        }
      }
      // residual gather for this half straight from LDS (bf16 already)
      {
        const int rlo = half ? nh : 0, rhi = half ? ns : nh;
        for (int r = rlo + tid; r < rhi; r += 256) {
          const int p = pl[r];
          const int gxl = (p >> 7) - half * 64, y = p & 127;
          rc[r] = imgL[gxl * 128 + (((y >> 3) ^ (gxl & 15))) * 8 + (y & 7)];
        }
      }
    }
  }
  __syncthreads();

  // x-pass MFMA: all 4 waves; wave w -> image (w>>1), tile-pair (w&1)
  {
    const int wi = w >> 1, wl = w & 1;
    FragU Gf[2];
    f32x4 acc2[2][2] = {};
#pragma unroll
    for (int ks = 0; ks < 4; ++ks) {
#pragma unroll
      for (int mtl = 0; mtl < 2; ++mtl)
        Gf[mtl].u = *(const uint4*)&Gtu[((wl + 2 * mtl) * 16 + (l & 15)) * 64 + ks * 16 + (l >> 4) * 4];
#pragma unroll
      for (int nt = 0; nt < 2; ++nt) {
        const int wp = nt * 16 + (l & 15);
        const int chunk = (ks * 4 + (l >> 4)) ^ (wp & 15);
        FragU bfr;
        bfr.u = *(const uint4*)&A1t[wi][wp * 128 + chunk * 8];
#pragma unroll
        for (int mtl = 0; mtl < 2; ++mtl)
          acc2[mtl][nt] = __builtin_amdgcn_mfma_f32_16x16x32_bf16(Gf[mtl].s, bfr.s, acc2[mtl][nt], 0, 0, 0);
      }
    }
#pragma unroll
    for (int r = 0; r < 4; ++r) {
      const int j = wl * 16 + (l >> 4) * 4 + r;   // kxi 0..31
      const int ky = l & 15;
      const float re = acc2[0][0][r] + acc2[1][1][r];
      const float im = acc2[0][1][r] - acc2[1][0][r];
      Xout[wi * 512 + j * 16 + ky] = pk(re, im);
    }
  }
  __syncthreads();
  {
    uint2* dst = (uint2*)(Xf + (size_t)((n << 6) + c0) * 512);
    const uint2* src = (const uint2*)Xout;
    dst[tid] = src[tid];
    dst[tid + 256] = src[tid + 256];
  }
}

// ---------------- Transpose Xf[bid][m] -> Xf2[m][bid] -------------------------
__global__ __launch_bounds__(256) void kt(const unsigned* __restrict__ Xf,
                                          unsigned* __restrict__ Xf2) {
  __shared__ unsigned tile[64 * 65];
  const int bm = blockIdx.x & 7, bn = blockIdx.x >> 3;
  const int tid = threadIdx.x;
  for (int i = 0; i < 16; ++i) {
    int idx = i * 256 + tid;
    int r = idx >> 6, cc = idx & 63;
    tile[r * 65 + cc] = Xf[(size_t)(bn * 64 + r) * 512 + bm * 64 + cc];
  }
  __syncthreads();
  for (int i = 0; i < 16; ++i) {
    int idx = i * 256 + tid;
    int r = idx >> 6, cc = idx & 63;
    Xf2[(size_t)(bm * 64 + r) * 4096 + bn * 64 + cc] = tile[cc * 65 + r];
  }
}

// ---------------- Stage 2: per-mode complex channel mix ------------------------
__global__ __launch_bounds__(256) void k2_mix(const unsigned* __restrict__ Xf2,
                                              const unsigned* __restrict__ Wt,
                                              unsigned* __restrict__ Yf) {
  __shared__ float2 Xs[64 * 65];
  __shared__ float2 Ws[64 * 65];
  const int m = blockIdx.x;
  const int tid = threadIdx.x;
  for (int i = 0; i < 16; ++i) {
    int e = i * 256 + tid;
    Xs[(e >> 6) * 65 + (e & 63)] = upk(Xf2[(size_t)m * 4096 + e]);
    Ws[(e >> 6) * 65 + (e & 63)] = upk(Wt[(size_t)m * 4096 + e]);
  }
  __syncthreads();
  const int g = tid >> 4, t = tid & 15;
  float accr[4][4] = {}, acci[4][4] = {};
  for (int cc = 0; cc < 64; ++cc) {
    float2 xv[4], wv[4];
#pragma unroll
    for (int k = 0; k < 4; ++k) xv[k] = Xs[(g + 16 * k) * 65 + cc];
#pragma unroll
    for (int j = 0; j < 4; ++j) wv[j] = Ws[(t + 16 * j) * 65 + cc];
#pragma unroll
    for (int k = 0; k < 4; ++k)
#pragma unroll
      for (int j = 0; j < 4; ++j) {
        accr[k][j] += xv[k].x * wv[j].x - xv[k].y * wv[j].y;
        acci[k][j] += xv[k].x * wv[j].y + xv[k].y * wv[j].x;
      }
  }
  __syncthreads();
  unsigned* Os = (unsigned*)Xs;
#pragma unroll
  for (int k = 0; k < 4; ++k)
#pragma unroll
    for (int j = 0; j < 4; ++j) {
      int bo = k * 64 + t + 16 * j;
      Os[bo * 17 + g] = pk(accr[k][j], acci[k][j]);
    }
  __syncthreads();
  for (int i = 0; i < 16; ++i) {
    int e = i * 256 + tid;
    int bo = e >> 4, ss = e & 15;
    Yf[(size_t)bo * 8192 + m * 16 + ss] = Os[bo * 17 + ss];
  }
}

// ---------------- Stage 3: MFMA inverse-x + per-pixel inverse-y + residual ----
__global__ __launch_bounds__(1024, 4) void k3_inv(const unsigned* __restrict__ Yf,
                                                  const unsigned* __restrict__ G2tu,
                                                  const int* __restrict__ scomb,
                                                  const unsigned short* __restrict__ Rcomp,
                                                  float* __restrict__ out) {
  __shared__ __align__(16) unsigned short Ypb[16 * 32 * 40]; // [s][col][kxi], pad-40
  __shared__ __align__(16) unsigned short tbuf[16 * 546];    // [s][16x][ky], u32-stride 273
  __shared__ float2 tab[128];
  const int bo = blockIdx.x >> 1, half = blockIdx.x & 1;
  const int tid = threadIdx.x;
  const int l = tid & 63, w = tid >> 6;    // w = wave id = s for phase A
  if (tid < 128) {
    float sv, cv;
    sincosf((float)tid * TWO_PI_OVER_128, &sv, &cv);
    tab[tid] = make_float2(cv, sv);
  }
  {
    const unsigned* src = Yf + (size_t)bo * 8192;
    for (int i = 0; i < 8; ++i) {
      int e = i * 1024 + tid;               // = m*16 + s
      unsigned v = src[e];
      int ss = e & 15, m = e >> 4, kxi = m >> 4, ky = m & 15;
      unsigned short* yb = Ypb + ss * 1280;
      yb[ky * 40 + kxi] = (unsigned short)(v & 0xFFFFu);
      yb[(16 + ky) * 40 + kxi] = (unsigned short)(v >> 16);
    }
  }
  __syncthreads();
  float* outb = out + (size_t)bo * 16384;
  const unsigned short* rcb = Rcomp + (size_t)bo * 16 * RCAP;
  unsigned* tb32 = (unsigned*)tbuf;

  for (int ch = 0; ch < 4; ++ch) {
    const int xb = half * 64 + ch * 16;
    // phase A: wave w computes t[s=w][16 x][16 ky] via 4 MFMAs
    {
      const int xg = xb + (l & 15);
      FragU Ac, As, B0, B1;
      Ac.u = *(const uint4*)&G2tu[xg * 32 + (l >> 4) * 4];
      As.u = *(const uint4*)&G2tu[xg * 32 + 16 + (l >> 4) * 4];
      const unsigned short* yb = Ypb + w * 1280;
      B0.u = *(const uint4*)&yb[(l & 15) * 40 + (l >> 4) * 8];
      B1.u = *(const uint4*)&yb[(16 + (l & 15)) * 40 + (l >> 4) * 8];
      f32x4 z = {};
      f32x4 d1  = __builtin_amdgcn_mfma_f32_16x16x32_bf16(Ac.s, B0.s, z, 0, 0, 0); // Σc·Yr
      f32x4 d1b = __builtin_amdgcn_mfma_f32_16x16x32_bf16(Ac.s, B1.s, z, 0, 0, 0); // Σc·Yi
      f32x4 d2  = __builtin_amdgcn_mfma_f32_16x16x32_bf16(As.s, B0.s, z, 0, 0, 0); // Σs·Yr
      f32x4 d2b = __builtin_amdgcn_mfma_f32_16x16x32_bf16(As.s, B1.s, z, 0, 0, 0); // Σs·Yi
      const int ky = l & 15;
#pragma unroll
      for (int r = 0; r < 4; ++r) {
        const int xloc = (l >> 4) * 4 + r;
        tb32[w * 273 + xloc * 17 + ky] = pk(d1[r] - d2b[r], d1b[r] + d2[r]);
      }
    }
    __syncthreads();
    // phase B: 16 x-rows × 128 y; wave w owns x-row w; 2 px/thread
    {
      const int xg = xb + w;
      const int pbase = xg * 128 + l * 2;
      const int2 sc2 = *(const int2*)&scomb[pbase];
      float o2[2];
#pragma unroll
      for (int q = 0; q < 2; ++q) {
        const int y = l * 2 + q;
        const int sc = q ? sc2.y : sc2.x;
        const int ssel = sc >> 12;
        const float rres = __uint_as_float((unsigned)rcb[ssel * RCAP + (sc & 4095)] << 16);
        const unsigned* tb = tb32 + ssel * 273 + w * 17;
        const float2 stpy = tab[y];
        float acc = 0.f, c0 = 1.f, s0 = 0.f;
#pragma unroll
        for (int k2 = 0; k2 < 16; ++k2) {
          const float2 tt = upk(tb[k2]);
          acc = fmaf(tt.x, c0, fmaf(-tt.y, s0, acc));
          float nc = c0 * stpy.x - s0 * stpy.y, ns = s0 * stpy.x + c0 * stpy.y;
          c0 = nc; s0 = ns;
        }
        o2[q] = rres + acc;
      }
      *(float2*)&outb[pbase] = make_float2(o2[0], o2[1]);
    }
    __syncthreads();
  }
}

extern "C" void kernel_launch(void* const* d_in, const int* in_sizes, int n_in,
                              void* d_out, int out_size, void* d_ws, size_t ws_size,
                              hipStream_t stream) {
  const float* ref = (const float*)d_in[0];
  const int* lu = (const int*)d_in[2];
  const float* w1r = (const float*)d_in[3];
  const float* w1i = (const float*)d_in[4];
  const float* w2r = (const float*)d_in[5];
  const float* w2i = (const float*)d_in[6];
  float* out = (float*)d_out;

  unsigned* Xf  = (unsigned*)d_ws;            // [4096][512]; reused as Yf after kt
  unsigned* Xf2 = Xf  + (size_t)4096 * 512;   // [512][4096]
  unsigned* Wt  = Xf2 + (size_t)4096 * 512;   // [512][64][64]
  unsigned* Etu = Wt  + (size_t)4096 * 512;   // 2048
  unsigned* Gtu = Etu + 2048;                 // 4096
  unsigned* G2tu = Gtu + 4096;                // 4096
  int* cntg     = (int*)(G2tu + 4096);        // 16
  int* cnthg    = cntg + 16;                  // 16
  int* plist    = cnthg + 16;                 // 16*RCAP
  int* scomb    = plist + 16 * RCAP;          // 16384
  unsigned short* Rcomp = (unsigned short*)(scomb + 16384);  // 256*16*RCAP bf16
  unsigned* Yf  = Xf;                          // alias (Xf dead after kt)

  kprep<<<145, 1024, 0, stream>>>(lu, scomb, plist, cntg, cnthg,
                                  Etu, Gtu, G2tu, w1r, w1i, w2r, w2i, Wt);
  k1_fwd<<<2048, 256, 0, stream>>>(ref, Etu, Gtu, cntg, cnthg, plist, Rcomp, Xf);
  kt<<<512, 256, 0, stream>>>(Xf, Xf2);
  k2_mix<<<512, 256, 0, stream>>>(Xf2, Wt, Yf);
  k3_inv<<<512, 1024, 0, stream>>>(Yf, G2tu, scomb, Rcomp, out);
}

// Round 8
// 113.080 us; speedup vs baseline: 3.1637x; 1.1431x over previous
//
#include <hip/hip_runtime.h>
#include <math.h>

// FNO spectral block: B=4, S=16, C=64, R=128, MODES=16
// bid = n*64+c, n = b*16+s. Mode slot m = kxi*16+ky, kx_eff = kxi<16 ? kxi : 96+kxi.
// K1: MFMA rfft2, 2 images/block. K2: MFMA per-mode channel mix. K3: MFMA inverse-x.

#define TWO_PI_OVER_128 0.04908738521234052f
#define RCAP 1280

typedef __attribute__((ext_vector_type(8))) short bf16x8;
typedef __attribute__((ext_vector_type(4))) float f32x4;
union FragU { uint4 u; bf16x8 s; };

__device__ __forceinline__ unsigned pk(float a, float b) {
  unsigned ua = __float_as_uint(a), ub = __float_as_uint(b);
  ua = (ua + 0x7FFFu + ((ua >> 16) & 1u)) >> 16;
  ub = (ub + 0x7FFFu + ((ub >> 16) & 1u)) >> 16;
  return ua | (ub << 16);
}
__device__ __forceinline__ float2 upk(unsigned v) {
  return make_float2(__uint_as_float(v << 16), __uint_as_float(v & 0xFFFF0000u));
}
__device__ __forceinline__ unsigned bf1(float a) {
  unsigned ua = __float_as_uint(a);
  return (ua + 0x7FFFu + ((ua >> 16) & 1u)) >> 16;
}

// ---------------- Fused prep: kscan (b<16) | ktab (b==16) | ktw (b>=17) --------
__global__ __launch_bounds__(1024) void kprep(const int* __restrict__ lu,
                                              int* __restrict__ scomb,
                                              int* __restrict__ plist,
                                              int* __restrict__ cntg,
                                              int* __restrict__ cnthg,
                                              unsigned* __restrict__ Etu,
                                              unsigned* __restrict__ Gtu,
                                              unsigned* __restrict__ G2tu,
                                              const float* __restrict__ w1r,
                                              const float* __restrict__ w1i,
                                              const float* __restrict__ w2r,
                                              const float* __restrict__ w2i,
                                              unsigned* __restrict__ Wt) {
  __shared__ int wsum[16];
  __shared__ unsigned tile[64 * 65];
  const int blk = blockIdx.x;
  const int tid = threadIdx.x;
  if (blk < 16) {
    // ---- scan: one block per s ----
    const int s = blk;
    const int lane = tid & 63, wid = tid >> 6;
    const int4* lu4 = (const int4*)lu + tid * 4;
    unsigned match = 0;
#pragma unroll
    for (int q = 0; q < 4; ++q) {
      int4 v = lu4[q];
      match |= (v.x == s ? 1u : 0u) << (4 * q);
      match |= (v.y == s ? 1u : 0u) << (4 * q + 1);
      match |= (v.z == s ? 1u : 0u) << (4 * q + 2);
      match |= (v.w == s ? 1u : 0u) << (4 * q + 3);
    }
    const int cnt = __popc(match);
    int pre = cnt;
#pragma unroll
    for (int d = 1; d < 64; d <<= 1) {
      int t = __shfl_up(pre, d, 64);
      if (lane >= d) pre += t;
    }
    if (lane == 63) wsum[wid] = pre;
    __syncthreads();
    int woff = 0;
    for (int j = 0; j < wid; ++j) woff += wsum[j];
    int r = woff + pre - cnt;
    if (tid == 512) cnthg[s] = r;
    const int base = tid * 16;
#pragma unroll
    for (int i = 0; i < 16; ++i) {
      if ((match >> i) & 1u) {
        const int p = base + i;
        scomb[p] = (s << 12) | r;
        if (r < RCAP) plist[s * RCAP + r] = p;
        ++r;
      }
    }
    if (tid == 1023) {
      const int tot = woff + pre;
      cntg[s] = (tot < RCAP) ? tot : RCAP;
    }
  } else if (blk == 16) {
    // ---- twiddle tables ----
    for (int i = 0; i < 2; ++i) {
      int t = i * 1024 + tid;
      int w = t >> 6, y0 = (t & 63) * 2;
      float v[2];
#pragma unroll
      for (int q = 0; q < 2; ++q) {
        int y = y0 + q;
        if (w < 16) v[q] = cosf((float)((w * y) & 127) * TWO_PI_OVER_128);
        else        v[q] = -sinf((float)(((w - 16) * y) & 127) * TWO_PI_OVER_128);
      }
      Etu[t] = bf1(v[0]) | (bf1(v[1]) << 16);
    }
    for (int i = 0; i < 4; ++i) {
      int t = i * 1024 + tid;
      int jr = t >> 6, x0 = (t & 63) * 2;
      int j = (jr & 31);
      int kx = (j < 16) ? j : 96 + j;
      float v[2];
#pragma unroll
      for (int q = 0; q < 2; ++q) {
        int x = x0 + q;
        float a = (float)((kx * x) & 127) * TWO_PI_OVER_128;
        v[q] = (jr < 32) ? cosf(a) : sinf(a);
      }
      Gtu[t] = bf1(v[0]) | (bf1(v[1]) << 16);
    }
    for (int i = 0; i < 4; ++i) {
      int t = i * 1024 + tid;               // u32 idx = x*32 + k2
      int x = t >> 5, k2 = t & 31;
      float v[2];
#pragma unroll
      for (int q = 0; q < 2; ++q) {
        int k = k2 * 2 + q;
        int kxi = k & 31;
        int kxe = (kxi < 16) ? kxi : 96 + kxi;
        float a = (float)((kxe * x) & 127) * TWO_PI_OVER_128;
        v[q] = (k < 32) ? cosf(a) : sinf(a);
      }
      G2tu[t] = bf1(v[0]) | (bf1(v[1]) << 16);
    }
  } else {
    // ---- weights transpose: old block (blk-17) in [0,128) ----
    const int ob = blk - 17;
    const int o = ob & 63, wsel = ob >> 6;
    const float* Wr = wsel ? w2r : w1r;
    const float* Wi = wsel ? w2i : w1i;
    for (int mc = 0; mc < 4; ++mc) {
      if (mc) __syncthreads();
      for (int i = 0; i < 4; ++i) {
        int idx = i * 1024 + tid;
        int c = idx >> 6, ml = idx & 63;
        int mh = mc * 64 + ml;
        float wsc = ((mh & 15) ? 2.f : 1.f) / 16384.f;
        size_t off = (size_t)(c * 64 + o) * 256 + mh;
        tile[c * 65 + ml] = pk(Wr[off] * wsc, Wi[off] * wsc);
      }
      __syncthreads();
      for (int i = 0; i < 4; ++i) {
        int idx = i * 1024 + tid;
        int ml = idx >> 6, c = idx & 63;
        Wt[(size_t)(wsel * 256 + mc * 64 + ml) * 4096 + o * 64 + c] = tile[c * 65 + ml];
      }
    }
  }
}

// ---------------- Stage 1: rfft2 via MFMA, 2 images/block ----------------------
__global__ __launch_bounds__(256, 4) void k1_fwd(const float* __restrict__ ref,
                                                 const unsigned* __restrict__ Etu,
                                                 const unsigned* __restrict__ Gtu,
                                                 const int* __restrict__ cntg,
                                                 const int* __restrict__ cnthg,
                                                 const int* __restrict__ plist,
                                                 unsigned short* __restrict__ Rcomp,
                                                 unsigned* __restrict__ Xf) {
  __shared__ unsigned short imgL[64 * 128];     // 16 KB staging (one half-image)
  __shared__ unsigned short A1t[2][32 * 128];   // per-image A1^T, 8 KB each
  unsigned* Xout = (unsigned*)imgL;             // alias; imgL dead before x-pass writes
  const int bid2 = blockIdx.x;                  // 0..2047
  const int n = bid2 >> 5, cp = bid2 & 31;
  const int c0 = cp * 2;
  const int b = n >> 4, s = n & 15;
  const int tid = threadIdx.x;
  const int l = tid & 63, w = tid >> 6;

  // Preload E fragments (B-operand) — live across both images
  FragU Ef[2][4];
#pragma unroll
  for (int nt = 0; nt < 2; ++nt)
#pragma unroll
    for (int ks = 0; ks < 4; ++ks)
      Ef[nt][ks].u = *(const uint4*)&Etu[(nt * 16 + (l & 15)) * 64 + ks * 16 + (l >> 4) * 4];

  const int ns = cntg[s], nh = cnthg[s];
  const int* pl = plist + s * RCAP;

  for (int img = 0; img < 2; ++img) {
    const int c = c0 + img;
    const float* imf = ref + (size_t)((n << 6) + c) * 16384;
    unsigned short* rc = Rcomp + ((size_t)((b << 6) + c) * 16 + s) * RCAP;
    for (int half = 0; half < 2; ++half) {
      if (img | half) __syncthreads();          // imgL free for re-stage
      const float4* im4 = (const float4*)(imf + half * 8192);
      for (int i = 0; i < 8; ++i) {
        const int e4 = i * 256 + tid;
        float4 v = im4[e4];
        const int pl2 = e4 * 4;
        const int xl = pl2 >> 7, y0 = pl2 & 127;
        const int chunk = (y0 >> 3) ^ (xl & 15);
        *(uint2*)&imgL[xl * 128 + chunk * 8 + (y0 & 7)] =
            make_uint2(pk(v.x, v.y), pk(v.z, v.w));
      }
      __syncthreads();
      // y-pass MFMA: wave w -> M-tile (half*4 + w)
      f32x4 acc1[2] = {};
      const int xl = w * 16 + (l & 15);
#pragma unroll
      for (int ks = 0; ks < 4; ++ks) {
        const int chunk = (ks * 4 + (l >> 4)) ^ (xl & 15);
        FragU a;
        a.u = *(const uint4*)&imgL[xl * 128 + chunk * 8];
#pragma unroll
        for (int nt = 0; nt < 2; ++nt)
          acc1[nt] = __builtin_amdgcn_mfma_f32_16x16x32_bf16(a.s, Ef[nt][ks].s, acc1[nt], 0, 0, 0);
      }
      {
        const int x0 = (half * 4 + w) * 16 + (l >> 4) * 4;
#pragma unroll
        for (int nt = 0; nt < 2; ++nt) {
          const int wp = nt * 16 + (l & 15);
          const int chunk = (x0 >> 3) ^ (wp & 15);
          *(uint2*)&A1t[img][wp * 128 + chunk * 8 + (x0 & 7)] =
              make_uint2(pk(acc1[nt][0], acc1[nt][1]), pk(acc1[nt][2], acc1[nt][3]));
        }
      }
      // residual gather for this half straight from LDS (bf16 already)
      {
        const int rlo = half ? nh : 0, rhi = half ? ns : nh;
        for (int r = rlo + tid; r < rhi; r += 256) {
          const int p = pl[r];
          const int gxl = (p >> 7) - half * 64, y = p & 127;
          rc[r] = imgL[gxl * 128 + (((y >> 3) ^ (gxl & 15))) * 8 + (y & 7)];
        }
      }
    }
  }
  __syncthreads();

  // x-pass MFMA: all 4 waves; wave w -> image (w>>1), tile-pair (w&1)
  {
    const int wi = w >> 1, wl = w & 1;
    FragU Gf[2];
    f32x4 acc2[2][2] = {};
#pragma unroll
    for (int ks = 0; ks < 4; ++ks) {
#pragma unroll
      for (int mtl = 0; mtl < 2; ++mtl)
        Gf[mtl].u = *(const uint4*)&Gtu[((wl + 2 * mtl) * 16 + (l & 15)) * 64 + ks * 16 + (l >> 4) * 4];
#pragma unroll
      for (int nt = 0; nt < 2; ++nt) {
        const int wp = nt * 16 + (l & 15);
        const int chunk = (ks * 4 + (l >> 4)) ^ (wp & 15);
        FragU bfr;
        bfr.u = *(const uint4*)&A1t[wi][wp * 128 + chunk * 8];
#pragma unroll
        for (int mtl = 0; mtl < 2; ++mtl)
          acc2[mtl][nt] = __builtin_amdgcn_mfma_f32_16x16x32_bf16(Gf[mtl].s, bfr.s, acc2[mtl][nt], 0, 0, 0);
      }
    }
#pragma unroll
    for (int r = 0; r < 4; ++r) {
      const int j = wl * 16 + (l >> 4) * 4 + r;   // kxi 0..31
      const int ky = l & 15;
      const float re = acc2[0][0][r] + acc2[1][1][r];
      const float im = acc2[0][1][r] - acc2[1][0][r];
      Xout[wi * 512 + j * 16 + ky] = pk(re, im);
    }
  }
  __syncthreads();
  {
    uint2* dst = (uint2*)(Xf + (size_t)((n << 6) + c0) * 512);
    const uint2* src = (const uint2*)Xout;
    dst[tid] = src[tid];
    dst[tid + 256] = src[tid + 256];
  }
}

// ---------------- Transpose Xf[bid][m] -> Xf2[m][bid] -------------------------
__global__ __launch_bounds__(256) void kt(const unsigned* __restrict__ Xf,
                                          unsigned* __restrict__ Xf2) {
  __shared__ unsigned tile[64 * 65];
  const int bm = blockIdx.x & 7, bn = blockIdx.x >> 3;
  const int tid = threadIdx.x;
  for (int i = 0; i < 16; ++i) {
    int idx = i * 256 + tid;
    int r = idx >> 6, cc = idx & 63;
    tile[r * 65 + cc] = Xf[(size_t)(bn * 64 + r) * 512 + bm * 64 + cc];
  }
  __syncthreads();
  for (int i = 0; i < 16; ++i) {
    int idx = i * 256 + tid;
    int r = idx >> 6, cc = idx & 63;
    Xf2[(size_t)(bm * 64 + r) * 4096 + bn * 64 + cc] = tile[cc * 65 + r];
  }
}

// ---------------- Stage 2: per-mode complex channel mix via MFMA ---------------
// Y[n][o] = sum_c X[n][c] * W[c][o]; Wt[m][o][c] holds W[c][o] (B-operand rows=o)
__global__ __launch_bounds__(256) void k2_mix(const unsigned* __restrict__ Xf2,
                                              const unsigned* __restrict__ Wt,
                                              unsigned* __restrict__ Yf) {
  __shared__ unsigned short Xr[64 * 64];  // [n][c], XOR-chunk swizzled (^ row&7)
  __shared__ unsigned short Xi[64 * 64];
  __shared__ unsigned short Wr[64 * 64];  // [o][c], same swizzle
  __shared__ unsigned short Wi[64 * 64];
  const int m = blockIdx.x;
  const int tid = threadIdx.x;
  const int l = tid & 63, w = tid >> 6;
  // Stage + de-interleave (re,im) pairs; uint2 loads, u32 LDS writes
  for (int i = 0; i < 8; ++i) {
    const int e0 = (i * 256 + tid) * 2;       // even element index, e = n*64+c
    const int n = e0 >> 6, cc = e0 & 63;
    const int pos = n * 64 + (((cc >> 3) ^ (n & 7)) << 3) + (cc & 7);
    uint2 xv = *(const uint2*)&Xf2[(size_t)m * 4096 + e0];
    *(unsigned*)&Xr[pos] = (xv.x & 0xFFFFu) | (xv.y << 16);
    *(unsigned*)&Xi[pos] = (xv.x >> 16) | (xv.y & 0xFFFF0000u);
    uint2 wv = *(const uint2*)&Wt[(size_t)m * 4096 + e0];
    *(unsigned*)&Wr[pos] = (wv.x & 0xFFFFu) | (wv.y << 16);
    *(unsigned*)&Wi[pos] = (wv.x >> 16) | (wv.y & 0xFFFF0000u);
  }
  __syncthreads();
  // Wave w owns M-tile rows n = w*16..w*16+15 (b = w)
  f32x4 acc[4][4] = {};  // [nt][P]: P0=XrWr P1=XiWi P2=XrWi P3=XiWr
  const int arow = w * 16 + (l & 15);
#pragma unroll
  for (int ks = 0; ks < 2; ++ks) {
    FragU Ar, Ai;
    {
      const int chunk = ((ks * 4 + (l >> 4))) ^ (arow & 7);
      Ar.u = *(const uint4*)&Xr[arow * 64 + chunk * 8];
      Ai.u = *(const uint4*)&Xi[arow * 64 + chunk * 8];
    }
#pragma unroll
    for (int nt = 0; nt < 4; ++nt) {
      const int orow = nt * 16 + (l & 15);
      const int chunk = ((ks * 4 + (l >> 4))) ^ (orow & 7);
      FragU Br, Bi;
      Br.u = *(const uint4*)&Wr[orow * 64 + chunk * 8];
      Bi.u = *(const uint4*)&Wi[orow * 64 + chunk * 8];
      acc[nt][0] = __builtin_amdgcn_mfma_f32_16x16x32_bf16(Ar.s, Br.s, acc[nt][0], 0, 0, 0);
      acc[nt][1] = __builtin_amdgcn_mfma_f32_16x16x32_bf16(Ai.s, Bi.s, acc[nt][1], 0, 0, 0);
      acc[nt][2] = __builtin_amdgcn_mfma_f32_16x16x32_bf16(Ar.s, Bi.s, acc[nt][2], 0, 0, 0);
      acc[nt][3] = __builtin_amdgcn_mfma_f32_16x16x32_bf16(Ai.s, Br.s, acc[nt][3], 0, 0, 0);
    }
  }
  // Epilogue: b=w, s = (l>>4)*4 + r, o = nt*16 + (l&15); lane-local uint4 store
#pragma unroll
  for (int nt = 0; nt < 4; ++nt) {
    unsigned o4[4];
#pragma unroll
    for (int r = 0; r < 4; ++r)
      o4[r] = pk(acc[nt][0][r] - acc[nt][1][r], acc[nt][2][r] + acc[nt][3][r]);
    const int bo = w * 64 + nt * 16 + (l & 15);
    *(uint4*)&Yf[(size_t)bo * 8192 + m * 16 + (l >> 4) * 4] = *(uint4*)o4;
  }
}

// ---------------- Stage 3: MFMA inverse-x + per-pixel inverse-y + residual ----
__global__ __launch_bounds__(1024, 4) void k3_inv(const unsigned* __restrict__ Yf,
                                                  const unsigned* __restrict__ G2tu,
                                                  const int* __restrict__ scomb,
                                                  const unsigned short* __restrict__ Rcomp,
                                                  float* __restrict__ out) {
  __shared__ __align__(16) unsigned short Ypb[16 * 32 * 40]; // [s][col][kxi], pad-40
  __shared__ __align__(16) unsigned short tbuf[16 * 546];    // [s][16x][ky], u32-stride 273
  __shared__ float2 tab[128];
  const int bo = blockIdx.x >> 1, half = blockIdx.x & 1;
  const int tid = threadIdx.x;
  const int l = tid & 63, w = tid >> 6;    // w = wave id = s for phase A
  if (tid < 128) {
    float sv, cv;
    sincosf((float)tid * TWO_PI_OVER_128, &sv, &cv);
    tab[tid] = make_float2(cv, sv);
  }
  {
    const unsigned* src = Yf + (size_t)bo * 8192;
    for (int i = 0; i < 8; ++i) {
      int e = i * 1024 + tid;               // = m*16 + s
      unsigned v = src[e];
      int ss = e & 15, m = e >> 4, kxi = m >> 4, ky = m & 15;
      unsigned short* yb = Ypb + ss * 1280;
      yb[ky * 40 + kxi] = (unsigned short)(v & 0xFFFFu);
      yb[(16 + ky) * 40 + kxi] = (unsigned short)(v >> 16);
    }
  }
  __syncthreads();
  float* outb = out + (size_t)bo * 16384;
  const unsigned short* rcb = Rcomp + (size_t)bo * 16 * RCAP;
  unsigned* tb32 = (unsigned*)tbuf;

  for (int ch = 0; ch < 4; ++ch) {
    const int xb = half * 64 + ch * 16;
    // phase A: wave w computes t[s=w][16 x][16 ky] via 4 MFMAs
    {
      const int xg = xb + (l & 15);
      FragU Ac, As, B0, B1;
      Ac.u = *(const uint4*)&G2tu[xg * 32 + (l >> 4) * 4];
      As.u = *(const uint4*)&G2tu[xg * 32 + 16 + (l >> 4) * 4];
      const unsigned short* yb = Ypb + w * 1280;
      B0.u = *(const uint4*)&yb[(l & 15) * 40 + (l >> 4) * 8];
      B1.u = *(const uint4*)&yb[(16 + (l & 15)) * 40 + (l >> 4) * 8];
      f32x4 z = {};
      f32x4 d1  = __builtin_amdgcn_mfma_f32_16x16x32_bf16(Ac.s, B0.s, z, 0, 0, 0); // Σc·Yr
      f32x4 d1b = __builtin_amdgcn_mfma_f32_16x16x32_bf16(Ac.s, B1.s, z, 0, 0, 0); // Σc·Yi
      f32x4 d2  = __builtin_amdgcn_mfma_f32_16x16x32_bf16(As.s, B0.s, z, 0, 0, 0); // Σs·Yr
      f32x4 d2b = __builtin_amdgcn_mfma_f32_16x16x32_bf16(As.s, B1.s, z, 0, 0, 0); // Σs·Yi
      const int ky = l & 15;
#pragma unroll
      for (int r = 0; r < 4; ++r) {
        const int xloc = (l >> 4) * 4 + r;
        tb32[w * 273 + xloc * 17 + ky] = pk(d1[r] - d2b[r], d1b[r] + d2[r]);
      }
    }
    __syncthreads();
    // phase B: 16 x-rows × 128 y; wave w owns x-row w; 2 px/thread
    {
      const int xg = xb + w;
      const int pbase = xg * 128 + l * 2;
      const int2 sc2 = *(const int2*)&scomb[pbase];
      float o2[2];
#pragma unroll
      for (int q = 0; q < 2; ++q) {
        const int y = l * 2 + q;
        const int sc = q ? sc2.y : sc2.x;
        const int ssel = sc >> 12;
        const float rres = __uint_as_float((unsigned)rcb[ssel * RCAP + (sc & 4095)] << 16);
        const unsigned* tb = tb32 + ssel * 273 + w * 17;
        const float2 stpy = tab[y];
        float acc = 0.f, c0 = 1.f, s0 = 0.f;
#pragma unroll
        for (int k2 = 0; k2 < 16; ++k2) {
          const float2 tt = upk(tb[k2]);
          acc = fmaf(tt.x, c0, fmaf(-tt.y, s0, acc));
          float nc = c0 * stpy.x - s0 * stpy.y, ns = s0 * stpy.x + c0 * stpy.y;
          c0 = nc; s0 = ns;
        }
        o2[q] = rres + acc;
      }
      *(float2*)&outb[pbase] = make_float2(o2[0], o2[1]);
    }
    __syncthreads();
  }
}

extern "C" void kernel_launch(void* const* d_in, const int* in_sizes, int n_in,
                              void* d_out, int out_size, void* d_ws, size_t ws_size,
                              hipStream_t stream) {
  const float* ref = (const float*)d_in[0];
  const int* lu = (const int*)d_in[2];
  const float* w1r = (const float*)d_in[3];
  const float* w1i = (const float*)d_in[4];
  const float* w2r = (const float*)d_in[5];
  const float* w2i = (const float*)d_in[6];
  float* out = (float*)d_out;

  unsigned* Xf  = (unsigned*)d_ws;            // [4096][512]; reused as Yf after kt
  unsigned* Xf2 = Xf  + (size_t)4096 * 512;   // [512][4096]
  unsigned* Wt  = Xf2 + (size_t)4096 * 512;   // [512][64][64]
  unsigned* Etu = Wt  + (size_t)4096 * 512;   // 2048
  unsigned* Gtu = Etu + 2048;                 // 4096
  unsigned* G2tu = Gtu + 4096;                // 4096
  int* cntg     = (int*)(G2tu + 4096);        // 16
  int* cnthg    = cntg + 16;                  // 16
  int* plist    = cnthg + 16;                 // 16*RCAP
  int* scomb    = plist + 16 * RCAP;          // 16384
  unsigned short* Rcomp = (unsigned short*)(scomb + 16384);  // 256*16*RCAP bf16
  unsigned* Yf  = Xf;                          // alias (Xf dead after kt)

  kprep<<<145, 1024, 0, stream>>>(lu, scomb, plist, cntg, cnthg,
                                  Etu, Gtu, G2tu, w1r, w1i, w2r, w2i, Wt);
  k1_fwd<<<2048, 256, 0, stream>>>(ref, Etu, Gtu, cntg, cnthg, plist, Rcomp, Xf);
  kt<<<512, 256, 0, stream>>>(Xf, Xf2);
  k2_mix<<<512, 256, 0, stream>>>(Xf2, Wt, Yf);
  k3_inv<<<512, 1024, 0, stream>>>(Yf, G2tu, scomb, Rcomp, out);
}

// Round 9
// 112.771 us; speedup vs baseline: 3.1724x; 1.0027x over previous
//
#include <hip/hip_runtime.h>
#include <math.h>

// FNO spectral block: B=4, S=16, C=64, R=128, MODES=16
// bid = n*64+c, n = b*16+s. Mode slot m = kxi*16+ky, kx_eff = kxi<16 ? kxi : 96+kxi.
// K1: MFMA rfft2, 2 images/block, async-staged. K2: MFMA channel mix.
// K3: MFMA inverse-x + y-paired VALU inverse-y + residual gather.

#define TWO_PI_OVER_128 0.04908738521234052f
#define RCAP 1280

typedef __attribute__((ext_vector_type(8))) short bf16x8;
typedef __attribute__((ext_vector_type(4))) float f32x4;
union FragU { uint4 u; bf16x8 s; };

__device__ __forceinline__ unsigned pk(float a, float b) {
  unsigned ua = __float_as_uint(a), ub = __float_as_uint(b);
  ua = (ua + 0x7FFFu + ((ua >> 16) & 1u)) >> 16;
  ub = (ub + 0x7FFFu + ((ub >> 16) & 1u)) >> 16;
  return ua | (ub << 16);
}
__device__ __forceinline__ float2 upk(unsigned v) {
  return make_float2(__uint_as_float(v << 16), __uint_as_float(v & 0xFFFF0000u));
}
__device__ __forceinline__ unsigned bf1(float a) {
  unsigned ua = __float_as_uint(a);
  return (ua + 0x7FFFu + ((ua >> 16) & 1u)) >> 16;
}

// ---------------- Fused prep: kscan (b<16) | ktab (b==16) | ktw (b>=17) --------
__global__ __launch_bounds__(1024) void kprep(const int* __restrict__ lu,
                                              int* __restrict__ scomb,
                                              int* __restrict__ plist,
                                              int* __restrict__ cntg,
                                              int* __restrict__ cnthg,
                                              unsigned* __restrict__ Etu,
                                              unsigned* __restrict__ Gtu,
                                              unsigned* __restrict__ G2tu,
                                              const float* __restrict__ w1r,
                                              const float* __restrict__ w1i,
                                              const float* __restrict__ w2r,
                                              const float* __restrict__ w2i,
                                              unsigned* __restrict__ Wt) {
  __shared__ int wsum[16];
  __shared__ unsigned tile[64 * 65];
  const int blk = blockIdx.x;
  const int tid = threadIdx.x;
  if (blk < 16) {
    const int s = blk;
    const int lane = tid & 63, wid = tid >> 6;
    const int4* lu4 = (const int4*)lu + tid * 4;
    unsigned match = 0;
#pragma unroll
    for (int q = 0; q < 4; ++q) {
      int4 v = lu4[q];
      match |= (v.x == s ? 1u : 0u) << (4 * q);
      match |= (v.y == s ? 1u : 0u) << (4 * q + 1);
      match |= (v.z == s ? 1u : 0u) << (4 * q + 2);
      match |= (v.w == s ? 1u : 0u) << (4 * q + 3);
    }
    const int cnt = __popc(match);
    int pre = cnt;
#pragma unroll
    for (int d = 1; d < 64; d <<= 1) {
      int t = __shfl_up(pre, d, 64);
      if (lane >= d) pre += t;
    }
    if (lane == 63) wsum[wid] = pre;
    __syncthreads();
    int woff = 0;
    for (int j = 0; j < wid; ++j) woff += wsum[j];
    int r = woff + pre - cnt;
    if (tid == 512) cnthg[s] = r;
    const int base = tid * 16;
#pragma unroll
    for (int i = 0; i < 16; ++i) {
      if ((match >> i) & 1u) {
        const int p = base + i;
        scomb[p] = (s << 12) | r;
        if (r < RCAP) plist[s * RCAP + r] = p;
        ++r;
      }
    }
    if (tid == 1023) {
      const int tot = woff + pre;
      cntg[s] = (tot < RCAP) ? tot : RCAP;
    }
  } else if (blk == 16) {
    for (int i = 0; i < 2; ++i) {
      int t = i * 1024 + tid;
      int w = t >> 6, y0 = (t & 63) * 2;
      float v[2];
#pragma unroll
      for (int q = 0; q < 2; ++q) {
        int y = y0 + q;
        if (w < 16) v[q] = cosf((float)((w * y) & 127) * TWO_PI_OVER_128);
        else        v[q] = -sinf((float)(((w - 16) * y) & 127) * TWO_PI_OVER_128);
      }
      Etu[t] = bf1(v[0]) | (bf1(v[1]) << 16);
    }
    for (int i = 0; i < 4; ++i) {
      int t = i * 1024 + tid;
      int jr = t >> 6, x0 = (t & 63) * 2;
      int j = (jr & 31);
      int kx = (j < 16) ? j : 96 + j;
      float v[2];
#pragma unroll
      for (int q = 0; q < 2; ++q) {
        int x = x0 + q;
        float a = (float)((kx * x) & 127) * TWO_PI_OVER_128;
        v[q] = (jr < 32) ? cosf(a) : sinf(a);
      }
      Gtu[t] = bf1(v[0]) | (bf1(v[1]) << 16);
    }
    for (int i = 0; i < 4; ++i) {
      int t = i * 1024 + tid;               // u32 idx = x*32 + k2
      int x = t >> 5, k2 = t & 31;
      float v[2];
#pragma unroll
      for (int q = 0; q < 2; ++q) {
        int k = k2 * 2 + q;
        int kxi = k & 31;
        int kxe = (kxi < 16) ? kxi : 96 + kxi;
        float a = (float)((kxe * x) & 127) * TWO_PI_OVER_128;
        v[q] = (k < 32) ? cosf(a) : sinf(a);
      }
      G2tu[t] = bf1(v[0]) | (bf1(v[1]) << 16);
    }
  } else {
    const int ob = blk - 17;
    const int o = ob & 63, wsel = ob >> 6;
    const float* Wr = wsel ? w2r : w1r;
    const float* Wi = wsel ? w2i : w1i;
    for (int mc = 0; mc < 4; ++mc) {
      if (mc) __syncthreads();
      for (int i = 0; i < 4; ++i) {
        int idx = i * 1024 + tid;
        int c = idx >> 6, ml = idx & 63;
        int mh = mc * 64 + ml;
        float wsc = ((mh & 15) ? 2.f : 1.f) / 16384.f;
        size_t off = (size_t)(c * 64 + o) * 256 + mh;
        tile[c * 65 + ml] = pk(Wr[off] * wsc, Wi[off] * wsc);
      }
      __syncthreads();
      for (int i = 0; i < 4; ++i) {
        int idx = i * 1024 + tid;
        int ml = idx >> 6, c = idx & 63;
        Wt[(size_t)(wsel * 256 + mc * 64 + ml) * 4096 + o * 64 + c] = tile[c * 65 + ml];
      }
    }
  }
}

// ---------------- Stage 1: rfft2 via MFMA, 2 images/block, async-staged -------
__global__ __launch_bounds__(256, 4) void k1_fwd(const float* __restrict__ ref,
                                                 const unsigned* __restrict__ Etu,
                                                 const unsigned* __restrict__ Gtu,
                                                 const int* __restrict__ cntg,
                                                 const int* __restrict__ cnthg,
                                                 const int* __restrict__ plist,
                                                 unsigned short* __restrict__ Rcomp,
                                                 unsigned* __restrict__ Xf) {
  __shared__ unsigned short imgL[64 * 128];     // 16 KB staging (one half-image)
  __shared__ unsigned short A1t[2][32 * 128];   // per-image A1^T, 8 KB each
  unsigned* Xout = (unsigned*)imgL;             // alias; imgL dead before x-pass writes
  const int bid2 = blockIdx.x;                  // 0..2047
  const int n = bid2 >> 5, cp = bid2 & 31;
  const int c0 = cp * 2;
  const int b = n >> 4, s = n & 15;
  const int tid = threadIdx.x;
  const int l = tid & 63, w = tid >> 6;

  // Preload E fragments (B-operand) — live across both images
  FragU Ef[2][4];
#pragma unroll
  for (int nt = 0; nt < 2; ++nt)
#pragma unroll
    for (int ks = 0; ks < 4; ++ks)
      Ef[nt][ks].u = *(const uint4*)&Etu[(nt * 16 + (l & 15)) * 64 + ks * 16 + (l >> 4) * 4];

  const int ns = cntg[s], nh = cnthg[s];
  const int* pl = plist + s * RCAP;
  const float* imf0 = ref + (size_t)((n << 6) + c0) * 16384;

  // T14 async-stage: prologue load of stage 0
  float4 v[8];
  {
    const float4* p = (const float4*)imf0;
#pragma unroll
    for (int i = 0; i < 8; ++i) v[i] = p[i * 256 + tid];
  }

  for (int st = 0; st < 4; ++st) {              // st = img*2 + half
    const int img = st >> 1, half = st & 1;
    if (st) __syncthreads();                    // imgL readers of st-1 done
    // LDS-write current stage from registers
#pragma unroll
    for (int i = 0; i < 8; ++i) {
      const int pl2 = (i * 256 + tid) * 4;
      const int xl = pl2 >> 7, y0 = pl2 & 127;
      const int chunk = (y0 >> 3) ^ (xl & 15);
      *(uint2*)&imgL[xl * 128 + chunk * 8 + (y0 & 7)] =
          make_uint2(pk(v[i].x, v[i].y), pk(v[i].z, v[i].w));
    }
    __syncthreads();                            // imgL ready
    // Issue next stage's loads now — latency hides under MFMA + gather below
    if (st < 3) {
      const int st2 = st + 1;
      const float4* p = (const float4*)(imf0 + (st2 >> 1) * 16384 + (st2 & 1) * 8192);
#pragma unroll
      for (int i = 0; i < 8; ++i) v[i] = p[i * 256 + tid];
    }
    // y-pass MFMA: wave w -> M-tile (half*4 + w)
    f32x4 acc1[2] = {};
    const int xl = w * 16 + (l & 15);
#pragma unroll
    for (int ks = 0; ks < 4; ++ks) {
      const int chunk = (ks * 4 + (l >> 4)) ^ (xl & 15);
      FragU a;
      a.u = *(const uint4*)&imgL[xl * 128 + chunk * 8];
#pragma unroll
      for (int nt = 0; nt < 2; ++nt)
        acc1[nt] = __builtin_amdgcn_mfma_f32_16x16x32_bf16(a.s, Ef[nt][ks].s, acc1[nt], 0, 0, 0);
    }
    {
      const int x0 = (half * 4 + w) * 16 + (l >> 4) * 4;
#pragma unroll
      for (int nt = 0; nt < 2; ++nt) {
        const int wp = nt * 16 + (l & 15);
        const int chunk = (x0 >> 3) ^ (wp & 15);
        *(uint2*)&A1t[img][wp * 128 + chunk * 8 + (x0 & 7)] =
            make_uint2(pk(acc1[nt][0], acc1[nt][1]), pk(acc1[nt][2], acc1[nt][3]));
      }
    }
    // residual gather for this (img,half) straight from LDS
    {
      unsigned short* rc = Rcomp + ((size_t)((b << 6) + c0 + img) * 16 + s) * RCAP;
      const int rlo = half ? nh : 0, rhi = half ? ns : nh;
      for (int r = rlo + tid; r < rhi; r += 256) {
        const int p = pl[r];
        const int gxl = (p >> 7) - half * 64, y = p & 127;
        rc[r] = imgL[gxl * 128 + (((y >> 3) ^ (gxl & 15))) * 8 + (y & 7)];
      }
    }
  }
  __syncthreads();

  // x-pass MFMA: all 4 waves; wave w -> image (w>>1), tile-pair (w&1)
  {
    const int wi = w >> 1, wl = w & 1;
    FragU Gf[2];
    f32x4 acc2[2][2] = {};
#pragma unroll
    for (int ks = 0; ks < 4; ++ks) {
#pragma unroll
      for (int mtl = 0; mtl < 2; ++mtl)
        Gf[mtl].u = *(const uint4*)&Gtu[((wl + 2 * mtl) * 16 + (l & 15)) * 64 + ks * 16 + (l >> 4) * 4];
#pragma unroll
      for (int nt = 0; nt < 2; ++nt) {
        const int wp = nt * 16 + (l & 15);
        const int chunk = (ks * 4 + (l >> 4)) ^ (wp & 15);
        FragU bfr;
        bfr.u = *(const uint4*)&A1t[wi][wp * 128 + chunk * 8];
#pragma unroll
        for (int mtl = 0; mtl < 2; ++mtl)
          acc2[mtl][nt] = __builtin_amdgcn_mfma_f32_16x16x32_bf16(Gf[mtl].s, bfr.s, acc2[mtl][nt], 0, 0, 0);
      }
    }
#pragma unroll
    for (int r = 0; r < 4; ++r) {
      const int j = wl * 16 + (l >> 4) * 4 + r;   // kxi 0..31
      const int ky = l & 15;
      const float re = acc2[0][0][r] + acc2[1][1][r];
      const float im = acc2[0][1][r] - acc2[1][0][r];
      Xout[wi * 512 + j * 16 + ky] = pk(re, im);
    }
  }
  __syncthreads();
  {
    uint2* dst = (uint2*)(Xf + (size_t)((n << 6) + c0) * 512);
    const uint2* src = (const uint2*)Xout;
    dst[tid] = src[tid];
    dst[tid + 256] = src[tid + 256];
  }
}

// ---------------- Transpose Xf[bid][m] -> Xf2[m][bid] -------------------------
__global__ __launch_bounds__(256) void kt(const unsigned* __restrict__ Xf,
                                          unsigned* __restrict__ Xf2) {
  __shared__ unsigned tile[64 * 65];
  const int bm = blockIdx.x & 7, bn = blockIdx.x >> 3;
  const int tid = threadIdx.x;
  for (int i = 0; i < 16; ++i) {
    int idx = i * 256 + tid;
    int r = idx >> 6, cc = idx & 63;
    tile[r * 65 + cc] = Xf[(size_t)(bn * 64 + r) * 512 + bm * 64 + cc];
  }
  __syncthreads();
  for (int i = 0; i < 16; ++i) {
    int idx = i * 256 + tid;
    int r = idx >> 6, cc = idx & 63;
    Xf2[(size_t)(bm * 64 + r) * 4096 + bn * 64 + cc] = tile[cc * 65 + r];
  }
}

// ---------------- Stage 2: per-mode complex channel mix via MFMA ---------------
__global__ __launch_bounds__(256) void k2_mix(const unsigned* __restrict__ Xf2,
                                              const unsigned* __restrict__ Wt,
                                              unsigned* __restrict__ Yf) {
  __shared__ unsigned short Xr[64 * 64];  // [n][c], XOR-chunk swizzled (^ row&7)
  __shared__ unsigned short Xi[64 * 64];
  __shared__ unsigned short Wr[64 * 64];  // [o][c]
  __shared__ unsigned short Wi[64 * 64];
  const int m = blockIdx.x;
  const int tid = threadIdx.x;
  const int l = tid & 63, w = tid >> 6;
  for (int i = 0; i < 8; ++i) {
    const int e0 = (i * 256 + tid) * 2;
    const int n = e0 >> 6, cc = e0 & 63;
    const int pos = n * 64 + (((cc >> 3) ^ (n & 7)) << 3) + (cc & 7);
    uint2 xv = *(const uint2*)&Xf2[(size_t)m * 4096 + e0];
    *(unsigned*)&Xr[pos] = (xv.x & 0xFFFFu) | (xv.y << 16);
    *(unsigned*)&Xi[pos] = (xv.x >> 16) | (xv.y & 0xFFFF0000u);
    uint2 wv = *(const uint2*)&Wt[(size_t)m * 4096 + e0];
    *(unsigned*)&Wr[pos] = (wv.x & 0xFFFFu) | (wv.y << 16);
    *(unsigned*)&Wi[pos] = (wv.x >> 16) | (wv.y & 0xFFFF0000u);
  }
  __syncthreads();
  f32x4 acc[4][4] = {};
  const int arow = w * 16 + (l & 15);
#pragma unroll
  for (int ks = 0; ks < 2; ++ks) {
    FragU Ar, Ai;
    {
      const int chunk = ((ks * 4 + (l >> 4))) ^ (arow & 7);
      Ar.u = *(const uint4*)&Xr[arow * 64 + chunk * 8];
      Ai.u = *(const uint4*)&Xi[arow * 64 + chunk * 8];
    }
#pragma unroll
    for (int nt = 0; nt < 4; ++nt) {
      const int orow = nt * 16 + (l & 15);
      const int chunk = ((ks * 4 + (l >> 4))) ^ (orow & 7);
      FragU Br, Bi;
      Br.u = *(const uint4*)&Wr[orow * 64 + chunk * 8];
      Bi.u = *(const uint4*)&Wi[orow * 64 + chunk * 8];
      acc[nt][0] = __builtin_amdgcn_mfma_f32_16x16x32_bf16(Ar.s, Br.s, acc[nt][0], 0, 0, 0);
      acc[nt][1] = __builtin_amdgcn_mfma_f32_16x16x32_bf16(Ai.s, Bi.s, acc[nt][1], 0, 0, 0);
      acc[nt][2] = __builtin_amdgcn_mfma_f32_16x16x32_bf16(Ar.s, Bi.s, acc[nt][2], 0, 0, 0);
      acc[nt][3] = __builtin_amdgcn_mfma_f32_16x16x32_bf16(Ai.s, Br.s, acc[nt][3], 0, 0, 0);
    }
  }
#pragma unroll
  for (int nt = 0; nt < 4; ++nt) {
    unsigned o4[4];
#pragma unroll
    for (int r = 0; r < 4; ++r)
      o4[r] = pk(acc[nt][0][r] - acc[nt][1][r], acc[nt][2][r] + acc[nt][3][r]);
    const int bo = w * 64 + nt * 16 + (l & 15);
    *(uint4*)&Yf[(size_t)bo * 8192 + m * 16 + (l >> 4) * 4] = *(uint4*)o4;
  }
}

// ---------------- Stage 3: MFMA inverse-x + y-paired inverse-y + residual -----
__global__ __launch_bounds__(1024, 4) void k3_inv(const unsigned* __restrict__ Yf,
                                                  const unsigned* __restrict__ G2tu,
                                                  const int* __restrict__ scomb,
                                                  const unsigned short* __restrict__ Rcomp,
                                                  float* __restrict__ out) {
  __shared__ __align__(16) unsigned short Ypb[16 * 32 * 40]; // [s][col][kxi], pad-40
  __shared__ __align__(16) unsigned short tbuf[16 * 546];    // [s][16x][ky], u32-stride 273
  __shared__ float2 tab[128];
  const int bo = blockIdx.x >> 1, half = blockIdx.x & 1;
  const int tid = threadIdx.x;
  const int l = tid & 63, w = tid >> 6;    // phase A: w = s; phase B: w = x-row
  if (tid < 128) {
    float sv, cv;
    sincosf((float)tid * TWO_PI_OVER_128, &sv, &cv);
    tab[tid] = make_float2(cv, sv);
  }
  {
    const unsigned* src = Yf + (size_t)bo * 8192;
    for (int i = 0; i < 8; ++i) {
      int e = i * 1024 + tid;               // = m*16 + s
      unsigned v = src[e];
      int ss = e & 15, m = e >> 4, kxi = m >> 4, ky = m & 15;
      unsigned short* yb = Ypb + ss * 1280;
      yb[ky * 40 + kxi] = (unsigned short)(v & 0xFFFFu);
      yb[(16 + ky) * 40 + kxi] = (unsigned short)(v >> 16);
    }
  }
  __syncthreads();
  float* outb = out + (size_t)bo * 16384;
  const unsigned short* rcb = Rcomp + (size_t)bo * 16 * RCAP;
  unsigned* tb32 = (unsigned*)tbuf;

  for (int ch = 0; ch < 4; ++ch) {
    const int xb = half * 64 + ch * 16;
    // phase A: wave w computes t[s=w][16 x][16 ky] via 4 MFMAs
    {
      const int xg = xb + (l & 15);
      FragU Ac, As, B0, B1;
      Ac.u = *(const uint4*)&G2tu[xg * 32 + (l >> 4) * 4];
      As.u = *(const uint4*)&G2tu[xg * 32 + 16 + (l >> 4) * 4];
      const unsigned short* yb = Ypb + w * 1280;
      B0.u = *(const uint4*)&yb[(l & 15) * 40 + (l >> 4) * 8];
      B1.u = *(const uint4*)&yb[(16 + (l & 15)) * 40 + (l >> 4) * 8];
      f32x4 z = {};
      f32x4 d1  = __builtin_amdgcn_mfma_f32_16x16x32_bf16(Ac.s, B0.s, z, 0, 0, 0); // Σc·Yr
      f32x4 d1b = __builtin_amdgcn_mfma_f32_16x16x32_bf16(Ac.s, B1.s, z, 0, 0, 0); // Σc·Yi
      f32x4 d2  = __builtin_amdgcn_mfma_f32_16x16x32_bf16(As.s, B0.s, z, 0, 0, 0); // Σs·Yr
      f32x4 d2b = __builtin_amdgcn_mfma_f32_16x16x32_bf16(As.s, B1.s, z, 0, 0, 0); // Σs·Yi
      const int ky = l & 15;
#pragma unroll
      for (int r = 0; r < 4; ++r) {
        const int xloc = (l >> 4) * 4 + r;
        tb32[w * 273 + xloc * 17 + ky] = pk(d1[r] - d2b[r], d1b[r] + d2[r]);
      }
    }
    __syncthreads();
    // phase B: wave w owns x-row w; lane l = y in [0,64), pair (y, y+64).
    // out(y+64) = sum_k (-1)^k Re(t_k e^{i phi_k y}) — rotation chain shared.
    {
      const int xg = xb + w;
      const int p0 = xg * 128 + l;
      const int sc0 = scomb[p0], sc1 = scomb[p0 + 64];
      const int ssa = sc0 >> 12, ssb = sc1 >> 12;
      const float r0 = __uint_as_float((unsigned)rcb[ssa * RCAP + (sc0 & 4095)] << 16);
      const float r1 = __uint_as_float((unsigned)rcb[ssb * RCAP + (sc1 & 4095)] << 16);
      const unsigned* tb0 = tb32 + ssa * 273 + w * 17;
      const unsigned* tb1 = tb32 + ssb * 273 + w * 17;
      const float2 stpy = tab[l];
      float acc0 = 0.f, acc1e = 0.f, acc1o = 0.f;
      float c0 = 1.f, s0 = 0.f;
#pragma unroll
      for (int k2 = 0; k2 < 16; ++k2) {
        const float2 ta = upk(tb0[k2]);
        const float2 tc = upk(tb1[k2]);
        acc0 = fmaf(ta.x, c0, fmaf(-ta.y, s0, acc0));
        if (k2 & 1) acc1o = fmaf(tc.x, c0, fmaf(-tc.y, s0, acc1o));
        else        acc1e = fmaf(tc.x, c0, fmaf(-tc.y, s0, acc1e));
        float nc = c0 * stpy.x - s0 * stpy.y, ns = s0 * stpy.x + c0 * stpy.y;
        c0 = nc; s0 = ns;
      }
      outb[p0] = r0 + acc0;
      outb[p0 + 64] = r1 + (acc1e - acc1o);
    }
    __syncthreads();
  }
}

extern "C" void kernel_launch(void* const* d_in, const int* in_sizes, int n_in,
                              void* d_out, int out_size, void* d_ws, size_t ws_size,
                              hipStream_t stream) {
  const float* ref = (const float*)d_in[0];
  const int* lu = (const int*)d_in[2];
  const float* w1r = (const float*)d_in[3];
  const float* w1i = (const float*)d_in[4];
  const float* w2r = (const float*)d_in[5];
  const float* w2i = (const float*)d_in[6];
  float* out = (float*)d_out;

  unsigned* Xf  = (unsigned*)d_ws;            // [4096][512]; reused as Yf after kt
  unsigned* Xf2 = Xf  + (size_t)4096 * 512;   // [512][4096]
  unsigned* Wt  = Xf2 + (size_t)4096 * 512;   // [512][64][64]
  unsigned* Etu = Wt  + (size_t)4096 * 512;   // 2048
  unsigned* Gtu = Etu + 2048;                 // 4096
  unsigned* G2tu = Gtu + 4096;                // 4096
  int* cntg     = (int*)(G2tu + 4096);        // 16
  int* cnthg    = cntg + 16;                  // 16
  int* plist    = cnthg + 16;                 // 16*RCAP
  int* scomb    = plist + 16 * RCAP;          // 16384
  unsigned short* Rcomp = (unsigned short*)(scomb + 16384);  // 256*16*RCAP bf16
  unsigned* Yf  = Xf;                          // alias (Xf dead after kt)

  kprep<<<145, 1024, 0, stream>>>(lu, scomb, plist, cntg, cnthg,
                                  Etu, Gtu, G2tu, w1r, w1i, w2r, w2i, Wt);
  k1_fwd<<<2048, 256, 0, stream>>>(ref, Etu, Gtu, cntg, cnthg, plist, Rcomp, Xf);
  kt<<<512, 256, 0, stream>>>(Xf, Xf2);
  k2_mix<<<512, 256, 0, stream>>>(Xf2, Wt, Yf);
  k3_inv<<<512, 1024, 0, stream>>>(Yf, G2tu, scomb, Rcomp, out);
}